// Round 4
// baseline (258.892 us; speedup 1.0000x reference)
//
#include <hip/hip_runtime.h>
#include <hip/hip_bf16.h>

typedef __bf16 bf16;
typedef bf16  bf16x8 __attribute__((ext_vector_type(8)));
typedef bf16  bf16x4 __attribute__((ext_vector_type(4)));
typedef bf16  bf16x2 __attribute__((ext_vector_type(2)));
typedef float f32x4  __attribute__((ext_vector_type(4)));
typedef float f32x16 __attribute__((ext_vector_type(16)));
typedef int   i32x4  __attribute__((ext_vector_type(4)));

#define MFMA16(a,b,c) __builtin_amdgcn_mfma_f32_16x16x32_bf16((a),(b),(c),0,0,0)
#define MFMA32(a,b,c) __builtin_amdgcn_mfma_f32_32x32x16_bf16((a),(b),(c),0,0,0)

#define GLDS16(gp, lp) __builtin_amdgcn_global_load_lds( \
    (const __attribute__((address_space(1))) void*)(void*)(gp), \
    (__attribute__((address_space(3))) void*)(lp), 16, 0, 0)

static __device__ __forceinline__ bf16x8 lds_frag(const char* p){
  i32x4 v = *(const i32x4*)p;
  return __builtin_bit_cast(bf16x8, v);
}
static __device__ __forceinline__ bf16x8 g_frag(const bf16* p){
  i32x4 v = *(const i32x4*)p;
  return __builtin_bit_cast(bf16x8, v);
}
static __device__ __forceinline__ unsigned pk_bf16(float a, float b){
  bf16x2 v = { (bf16)a, (bf16)b };
  return __builtin_bit_cast(unsigned, v);
}
// swap upper 32 lanes of a with lower 32 lanes of b (gfx950)
static __device__ __forceinline__ void p32swap(unsigned &a, unsigned &b){
  asm("v_permlane32_swap_b32 %0, %1" : "+v"(a), "+v"(b));
}

// ---------------- min/max reduction (order-independent -> deterministic) ---
__device__ __forceinline__ unsigned fmap(float f){
  unsigned u = __float_as_uint(f);
  return (u & 0x80000000u) ? ~u : (u | 0x80000000u);
}
__device__ __forceinline__ float funmap(unsigned m){
  unsigned u = (m & 0x80000000u) ? (m & 0x7FFFFFFFu) : ~m;
  return __uint_as_float(u);
}

__global__ void init_mm(unsigned* mm){
  if (threadIdx.x == 0){
    mm[0] = 0xFFFFFFFFu; mm[1] = 0u;   // w_qkv min,max (mapped)
    mm[2] = 0xFFFFFFFFu; mm[3] = 0u;   // w_out min,max
  }
}

__global__ void minmax_k(const float* __restrict__ w, int n, unsigned* __restrict__ mm){
  __shared__ unsigned smn[256], smx[256];
  int tid = threadIdx.x;
  unsigned lmn = 0xFFFFFFFFu, lmx = 0u;
  for (int i = blockIdx.x * blockDim.x + tid; i < n; i += gridDim.x * blockDim.x){
    unsigned u = fmap(w[i]);
    lmn = min(lmn, u); lmx = max(lmx, u);
  }
  smn[tid] = lmn; smx[tid] = lmx;
  __syncthreads();
  for (int s = 128; s > 0; s >>= 1){
    if (tid < s){
      smn[tid] = min(smn[tid], smn[tid + s]);
      smx[tid] = max(smx[tid], smx[tid + s]);
    }
    __syncthreads();
  }
  if (tid == 0){ atomicMin(&mm[0], smn[0]); atomicMax(&mm[1], smx[0]); }
}

// ------------- fake-quant dequant + transpose + cast to bf16 ---------------
__global__ void dq_t(const float* __restrict__ w, bf16* __restrict__ wt,
                     int R, int C, const unsigned* __restrict__ mm){
  __shared__ float t[32][33];
  float xmin = funmap(mm[0]);
  float xmax = funmap(mm[1]);
  float scale = (xmax - xmin) / 255.0f;
  float denom = scale + 1e-8f;
  int ct = blockIdx.x * 32, rt = blockIdx.y * 32;
  int tx = threadIdx.x, ty = threadIdx.y;   // 32 x 8
#pragma unroll
  for (int p = 0; p < 4; ++p){
    int r = rt + p * 8 + ty;
    float x = w[(size_t)r * C + ct + tx];
    float q = rintf(fminf(fmaxf((x - xmin) / denom, 0.0f), 255.0f));
    t[p * 8 + ty][tx] = q * scale + xmin;
  }
  __syncthreads();
#pragma unroll
  for (int p = 0; p < 4; ++p){
    int c = p * 8 + ty;
    wt[(size_t)(ct + c) * R + rt + tx] = (bf16)t[tx][c];
  }
}

// ---------------- cast x (f32) -> bf16, vectorized x4 ----------------------
__global__ void cast_x(const float* __restrict__ x, bf16* __restrict__ xb, int n4){
  int i = blockIdx.x * 256 + threadIdx.x;
  if (i < n4){
    f32x4 v = *(const f32x4*)(x + (size_t)i * 4);
    bf16x4 o = { (bf16)v.x, (bf16)v.y, (bf16)v.z, (bf16)v.w };
    *(bf16x4*)(xb + (size_t)i * 4) = o;
  }
}

// ---------------- rope tables ----------------------------------------------
__global__ void sincos_k(float* __restrict__ sintab, float* __restrict__ costab){
  int idx = blockIdx.x * 256 + threadIdx.x;   // s*32 + i, 65536 total
  int i = idx & 31, s = idx >> 5;
  float invf = powf(10000.0f, -(float)i / 32.0f);
  float fr = (float)s * invf;
  sintab[idx] = sinf(fr);
  costab[idx] = cosf(fr);
}

// ------------- rope + reshape QKV(f32) -> Qr,Kr (B,H,S,D) bf16 -------------
// Q pre-scaled by (1/sqrt(D)) * log2(e) so attn uses exp2 directly.
__global__ void rope_qk(const float* __restrict__ qkv,
                        const float* __restrict__ sintab, const float* __restrict__ costab,
                        bf16* __restrict__ Qr, bf16* __restrict__ Kr){
  int idx = blockIdx.x * 256 + threadIdx.x;   // (bh*2048 + s)*32 + i
  int i  = idx & 31;
  int s  = (idx >> 5) & 2047;
  int bh = idx >> 16;
  int b = bh >> 4, h = bh & 15;
  const float QS = 0.18033688011f;   // 0.125 * log2(e)
  const float* row = qkv + (size_t)(b * 2048 + s) * 3072 + h * 64;
  float q1 = row[i],        q2 = row[32 + i];
  float k1 = row[1024 + i], k2 = row[1024 + 32 + i];
  float sn = sintab[s * 32 + i], cs = costab[s * 32 + i];
  size_t o = ((size_t)bh * 2048 + s) * 64 + i;
  Qr[o]      = (bf16)((q1 * cs - q2 * sn) * QS);
  Qr[o + 32] = (bf16)((q1 * sn + q2 * cs) * QS);
  Kr[o]      = (bf16)(k1 * cs - k2 * sn);
  Kr[o + 32] = (bf16)(k1 * sn + k2 * cs);
}

// ------------- V transpose: QKV(f32) -> Vt (B,H,D,S) bf16 ------------------
__global__ void vtrans(const float* __restrict__ qkv, bf16* __restrict__ Vt){
  __shared__ float t[64][65];
  int bh = blockIdx.x >> 5;
  int st = (blockIdx.x & 31) * 64;
  int b = bh >> 4, h = bh & 15;
  int tx = threadIdx.x & 63, ty4 = threadIdx.x >> 6;
#pragma unroll
  for (int p = 0; p < 16; ++p){
    int s = p * 4 + ty4;
    t[s][tx] = qkv[(size_t)(b * 2048 + st + s) * 3072 + 2048 + h * 64 + tx];
  }
  __syncthreads();
#pragma unroll
  for (int p = 0; p < 16; ++p){
    int d = p * 4 + ty4;
    Vt[((size_t)bh * 64 + d) * 2048 + st + tx] = (bf16)t[tx][d];
  }
}

// ---------------- bf16 MFMA GEMM, C = A * Bt^T (unchanged) -----------------
__global__ __launch_bounds__(256, 2) void gemm_bt(
    const bf16* __restrict__ A, const bf16* __restrict__ Bt,
    float* __restrict__ C, int M, int N, int K)
{
  __shared__ __align__(16) char lds[32768];
  int nbx = N >> 7;
  int bid = blockIdx.x;
  int nwg = gridDim.x;
  if ((nwg & 7) == 0){ int q = nwg >> 3; bid = (bid & 7) * q + (bid >> 3); }
  int row0 = (bid / nbx) << 7;
  int col0 = (bid % nbx) << 7;
  int tid = threadIdx.x, lane = tid & 63, wid = tid >> 6;
  int wr = (wid >> 1) * 64, wc = (wid & 1) * 64;
  int lr = lane & 15, g = lane >> 4;

  int aoff[2][4], boff[2][4];
#pragma unroll
  for (int kk = 0; kk < 2; ++kk){
#pragma unroll
    for (int m = 0; m < 4; ++m){
      int ra = wr + m * 16 + lr;
      aoff[kk][m] = ra * 128 + ((((kk * 4 + g) ^ ((ra >> 1) & 7))) << 4);
      int rb = wc + m * 16 + lr;
      boff[kk][m] = 16384 + rb * 128 + ((((kk * 4 + g) ^ ((rb >> 1) & 7))) << 4);
    }
  }

  const bf16* pA[4]; const bf16* pB[4]; int loff[4];
#pragma unroll
  for (int is = 0; is < 4; ++is){
    int f = is * 4096 + wid * 1024 + lane * 16;
    int r = f >> 7, c = (f >> 4) & 7;
    int cg = c ^ ((r >> 1) & 7);
    pA[is] = A  + (size_t)(row0 + r) * K + cg * 8;
    pB[is] = Bt + (size_t)(col0 + r) * K + cg * 8;
    loff[is] = is * 4096 + wid * 1024;
  }

  f32x4 acc[4][4] = {};
  for (int kt = 0; kt < K; kt += 64){
    __syncthreads();
#pragma unroll
    for (int is = 0; is < 4; ++is){
      GLDS16(pA[is] + kt, lds + loff[is]);
      GLDS16(pB[is] + kt, lds + 16384 + loff[is]);
    }
    __syncthreads();
#pragma unroll
    for (int kk = 0; kk < 2; ++kk){
      bf16x8 af[4], bfb[4];
#pragma unroll
      for (int m = 0; m < 4; ++m) af[m] = lds_frag(lds + aoff[kk][m]);
#pragma unroll
      for (int n = 0; n < 4; ++n) bfb[n] = lds_frag(lds + boff[kk][n]);
#pragma unroll
      for (int m = 0; m < 4; ++m)
#pragma unroll
        for (int n = 0; n < 4; ++n)
          acc[m][n] = MFMA16(af[m], bfb[n], acc[m][n]);
    }
  }

#pragma unroll
  for (int m = 0; m < 4; ++m){
    int row = row0 + wr + m * 16 + g * 4;
#pragma unroll
    for (int n = 0; n < 4; ++n){
      int col = col0 + wc + n * 16 + lr;
      float* cp = C + (size_t)row * N + col;
#pragma unroll
      for (int r = 0; r < 4; ++r)
        cp[(size_t)r * N] = acc[m][n][r];
    }
  }
}

// ---------------- flash attention, KV-split x4 + LDS merge -----------------
// grid: 2048 blocks (32 bh x 64 q-tiles); block = 4 waves sharing 32 queries,
// each wave owns a 512-key chunk with private online-softmax state.
// 32x32 MFMA, q = lane&31 per-lane softmax (tree reductions, defer-max THR=8
// in log2 domain), P fix-up via cvt_pk + v_permlane32_swap. End: m/l/O merge
// through LDS (33 KB -> 4 blocks/CU -> 32 waves/CU).
#define LOADK(KF, kvoff) do { _Pragma("unroll") \
    for (int t = 0; t < 4; ++t) \
      KF[t] = g_frag(Kb + (size_t)((kvoff) + l31) * 64 + t * 16 + hi8); } while(0)

#define LOADV(VF, kvoff) do { _Pragma("unroll") \
    for (int u = 0; u < 4; ++u) \
      VF[u] = g_frag(Vb + (size_t)((u & 1) * 32 + l31) * 2048 + (kvoff) + (u >> 1) * 16 + hi8); } while(0)

#define ATTN_TILE(KF, VF) do {                                               \
    f32x16 sc = {};                                                          \
    _Pragma("unroll")                                                        \
    for (int tt = 0; tt < 4; ++tt) sc = MFMA32(KF[tt], qf[tt], sc);          \
    float a0 = fmaxf(sc[0],sc[1]),  a1 = fmaxf(sc[2],sc[3]);                 \
    float a2 = fmaxf(sc[4],sc[5]),  a3 = fmaxf(sc[6],sc[7]);                 \
    float a4 = fmaxf(sc[8],sc[9]),  a5 = fmaxf(sc[10],sc[11]);               \
    float a6 = fmaxf(sc[12],sc[13]),a7 = fmaxf(sc[14],sc[15]);               \
    a0 = fmaxf(a0,a1); a2 = fmaxf(a2,a3); a4 = fmaxf(a4,a5); a6 = fmaxf(a6,a7);\
    a0 = fmaxf(a0,a2); a4 = fmaxf(a4,a6);                                    \
    float mt = fmaxf(a0,a4);                                                 \
    mt = fmaxf(mt, __shfl_xor(mt, 32));                                      \
    if (!__all(mt - mrun <= 8.0f)){                                          \
      float mn = fmaxf(mrun, mt);                                            \
      float cr = __builtin_amdgcn_exp2f(mrun - mn);                          \
      _Pragma("unroll")                                                      \
      for (int r = 0; r < 16; ++r){ o0[r] *= cr; o1[r] *= cr; }              \
      lrun *= cr; mrun = mn;                                                 \
    }                                                                        \
    _Pragma("unroll")                                                        \
    for (int r = 0; r < 16; ++r) sc[r] = __builtin_amdgcn_exp2f(sc[r] - mrun);\
    float s0 = (sc[0]+sc[1])+(sc[2]+sc[3]),   s1 = (sc[4]+sc[5])+(sc[6]+sc[7]);\
    float s2 = (sc[8]+sc[9])+(sc[10]+sc[11]), s3 = (sc[12]+sc[13])+(sc[14]+sc[15]);\
    float ps = (s0+s1)+(s2+s3);                                              \
    ps += __shfl_xor(ps, 32);                                                \
    lrun += ps;                                                              \
    _Pragma("unroll")                                                        \
    for (int kh = 0; kh < 2; ++kh){                                          \
      unsigned pa0 = pk_bf16(sc[kh*8+0], sc[kh*8+1]);                        \
      unsigned pa1 = pk_bf16(sc[kh*8+2], sc[kh*8+3]);                        \
      unsigned pb0 = pk_bf16(sc[kh*8+4], sc[kh*8+5]);                        \
      unsigned pb1 = pk_bf16(sc[kh*8+6], sc[kh*8+7]);                        \
      p32swap(pa0, pb0); p32swap(pa1, pb1);                                  \
      i32x4 wv = { (int)pa0, (int)pa1, (int)pb0, (int)pb1 };                 \
      bf16x8 pf = __builtin_bit_cast(bf16x8, wv);                            \
      o0 = MFMA32(VF[kh*2+0], pf, o0);                                       \
      o1 = MFMA32(VF[kh*2+1], pf, o1);                                       \
    }                                                                        \
  } while(0)

__global__ __launch_bounds__(256, 4) void attn_k(
    const bf16* __restrict__ Q, const bf16* __restrict__ K,
    const bf16* __restrict__ Vt, bf16* __restrict__ AO)
{
  __shared__ float mlds[4][2][32];                 // [wave][m/l][q]
  __shared__ float invL[32];
  __shared__ __align__(16) float Olds[4][64][32];  // [wave][d][q]  32 KB

  int bid = blockIdx.x;
  bid = (bid & 7) * 256 + (bid >> 3);     // XCD chunking: 4 heads per XCD
  int bh = bid >> 6;                      // 64 q-tiles per (b,h)
  int qblk = bid & 63;
  int b = bh >> 4, h = bh & 15;
  int tid = threadIdx.x, lane = tid & 63, wid = tid >> 6;
  int l31 = lane & 31, hi = lane >> 5, hi8 = hi * 8;
  int q0 = qblk * 32;

  const bf16* Qb = Q  + ((size_t)bh * 2048 + q0) * 64;
  const bf16* Kb = K  + (size_t)bh * 2048 * 64;
  const bf16* Vb = Vt + (size_t)bh * 64 * 2048;

  // Q B-frags: col = q (lane&31), d = t*16 + hi*8 + j (pre-scaled)
  bf16x8 qf[4];
#pragma unroll
  for (int t = 0; t < 4; ++t)
    qf[t] = g_frag(Qb + (size_t)l31 * 64 + t * 16 + hi8);

  f32x16 o0 = {}, o1 = {};     // O[d 0..31][q], O[d 32..63][q]
  float mrun = -1e30f, lrun = 0.0f;

  int kv0 = wid * 512;         // this wave's key chunk
  bf16x8 kfA[4], kfB[4], vf[4];
  LOADK(kfA, kv0);

  for (int t = 0; t < 16; t += 2){
    int kv = kv0 + t * 32;
    LOADV(vf, kv);
    LOADK(kfB, kv + 32);
    ATTN_TILE(kfA, vf);
    LOADV(vf, kv + 32);
    if (t < 14) LOADK(kfA, kv + 64);
    ATTN_TILE(kfB, vf);
  }

  // ---- cross-wave merge through LDS ----
  if (lane < 32){ mlds[wid][0][l31] = mrun; mlds[wid][1][l31] = lrun; }
  __syncthreads();
  float M = fmaxf(fmaxf(mlds[0][0][l31], mlds[1][0][l31]),
                  fmaxf(mlds[2][0][l31], mlds[3][0][l31]));
  float L = mlds[0][1][l31] * __builtin_amdgcn_exp2f(mlds[0][0][l31] - M)
          + mlds[1][1][l31] * __builtin_amdgcn_exp2f(mlds[1][0][l31] - M)
          + mlds[2][1][l31] * __builtin_amdgcn_exp2f(mlds[2][0][l31] - M)
          + mlds[3][1][l31] * __builtin_amdgcn_exp2f(mlds[3][0][l31] - M);
  if (wid == 0 && lane < 32) invL[l31] = 1.0f / L;
  float ew = __builtin_amdgcn_exp2f(mrun - M);
#pragma unroll
  for (int r = 0; r < 16; ++r){
    int d = 8 * (r >> 2) + 4 * hi + (r & 3);
    Olds[wid][d][l31]      = o0[r] * ew;
    Olds[wid][d + 32][l31] = o1[r] * ew;
  }
  __syncthreads();
  // merge + write: thread -> q = tid&31, d = (tid>>5)*8 .. +7
  int q = tid & 31, dbase = (tid >> 5) * 8;
  float iL = invL[q];
  bf16x8 ov;
#pragma unroll
  for (int j = 0; j < 8; ++j){
    int d = dbase + j;
    float s = ((Olds[0][d][q] + Olds[1][d][q]) + (Olds[2][d][q] + Olds[3][d][q]));
    ov[j] = (bf16)(s * iL);
  }
  *(bf16x8*)(AO + (size_t)(b * 2048 + q0 + q) * 1024 + h * 64 + dbase) = ov;
}

// ---------------------------------------------------------------------------
extern "C" void kernel_launch(void* const* d_in, const int* in_sizes, int n_in,
                              void* d_out, int out_size, void* d_ws, size_t ws_size,
                              hipStream_t stream) {
  const float* x     = (const float*)d_in[0];   // (2,2048,1024)
  const float* w_qkv = (const float*)d_in[1];   // (1024,3072)
  const float* w_out = (const float*)d_in[2];   // (1024,1024)
  float* out = (float*)d_out;                   // (2,2048,1024) f32

  char* ws = (char*)d_ws;
  const size_t MB = 1u << 20;
  unsigned* mm   = (unsigned*)(ws);              // 4 u32
  float* sintab  = (float*)(ws + 256);           // 256 KiB
  float* costab  = (float*)(ws + 256 + 262144);
  bf16* xb       = (bf16*)(ws + 1 * MB);         // 8 MiB
  bf16* wqkvT    = (bf16*)(ws + 9 * MB);         // 6 MiB  (3072 x 1024)
  bf16* woutT    = (bf16*)(ws + 15 * MB);        // 2 MiB  (1024 x 1024)
  float* qkvf    = (float*)(ws + 17 * MB);       // 48 MiB (4096 x 3072)
  bf16* Qr       = (bf16*)(ws + 65 * MB);        // 8 MiB  (32,2048,64)
  bf16* Kr       = (bf16*)(ws + 73 * MB);        // 8 MiB
  bf16* Vt       = (bf16*)(ws + 81 * MB);        // 8 MiB  (32,64,2048)
  bf16* AO       = (bf16*)(ws + 1 * MB);         // overlay on xb (dead after gemm1)

  init_mm<<<1, 64, 0, stream>>>(mm);
  minmax_k<<<512, 256, 0, stream>>>(w_qkv, 1024 * 3072, mm);
  minmax_k<<<512, 256, 0, stream>>>(w_out, 1024 * 1024, mm + 2);
  sincos_k<<<256, 256, 0, stream>>>(sintab, costab);
  cast_x<<<4096, 256, 0, stream>>>(x, xb, 4194304 / 4);
  dq_t<<<dim3(96, 32), dim3(32, 8), 0, stream>>>(w_qkv, wqkvT, 1024, 3072, mm);
  dq_t<<<dim3(32, 32), dim3(32, 8), 0, stream>>>(w_out, woutT, 1024, 1024, mm + 2);
  gemm_bt<<<768, 256, 0, stream>>>(xb, wqkvT, qkvf, 4096, 3072, 1024);
  rope_qk<<<8192, 256, 0, stream>>>(qkvf, sintab, costab, Qr, Kr);
  vtrans<<<1024, 256, 0, stream>>>(qkvf, Vt);
  attn_k<<<2048, 256, 0, stream>>>(Qr, Kr, Vt, AO);
  gemm_bt<<<256, 256, 0, stream>>>(AO, woutT, out, 4096, 1024, 1024);

  (void)in_sizes; (void)n_in; (void)out_size; (void)ws_size;
}

// Round 5
// 240.008 us; speedup vs baseline: 1.0787x; 1.0787x over previous
//
#include <hip/hip_runtime.h>
#include <hip/hip_bf16.h>

typedef __bf16 bf16;
typedef bf16  bf16x8 __attribute__((ext_vector_type(8)));
typedef bf16  bf16x4 __attribute__((ext_vector_type(4)));
typedef bf16  bf16x2 __attribute__((ext_vector_type(2)));
typedef float f32x4  __attribute__((ext_vector_type(4)));
typedef float f32x16 __attribute__((ext_vector_type(16)));
typedef int   i32x4  __attribute__((ext_vector_type(4)));

#define MFMA16(a,b,c) __builtin_amdgcn_mfma_f32_16x16x32_bf16((a),(b),(c),0,0,0)
#define MFMA32(a,b,c) __builtin_amdgcn_mfma_f32_32x32x16_bf16((a),(b),(c),0,0,0)

#define GLDS16(gp, lp) __builtin_amdgcn_global_load_lds( \
    (const __attribute__((address_space(1))) void*)(void*)(gp), \
    (__attribute__((address_space(3))) void*)(lp), 16, 0, 0)

static __device__ __forceinline__ bf16x8 lds_frag(const char* p){
  i32x4 v = *(const i32x4*)p;
  return __builtin_bit_cast(bf16x8, v);
}
static __device__ __forceinline__ bf16x8 g_frag(const bf16* p){
  i32x4 v = *(const i32x4*)p;
  return __builtin_bit_cast(bf16x8, v);
}
static __device__ __forceinline__ unsigned pk_bf16(float a, float b){
  bf16x2 v = { (bf16)a, (bf16)b };
  return __builtin_bit_cast(unsigned, v);
}
// swap upper 32 lanes of a with lower 32 lanes of b (gfx950)
static __device__ __forceinline__ void p32swap(unsigned &a, unsigned &b){
  asm("v_permlane32_swap_b32 %0, %1" : "+v"(a), "+v"(b));
}

// ---------------- min/max reduction (order-independent -> deterministic) ---
__device__ __forceinline__ unsigned fmap(float f){
  unsigned u = __float_as_uint(f);
  return (u & 0x80000000u) ? ~u : (u | 0x80000000u);
}
__device__ __forceinline__ float funmap(unsigned m){
  unsigned u = (m & 0x80000000u) ? (m & 0x7FFFFFFFu) : ~m;
  return __uint_as_float(u);
}

__global__ void init_mm(unsigned* mm){
  if (threadIdx.x == 0){
    mm[0] = 0xFFFFFFFFu; mm[1] = 0u;   // w_qkv min,max (mapped)
    mm[2] = 0xFFFFFFFFu; mm[3] = 0u;   // w_out min,max
  }
}

__global__ void minmax_k(const float* __restrict__ w, int n, unsigned* __restrict__ mm){
  __shared__ unsigned smn[256], smx[256];
  int tid = threadIdx.x;
  unsigned lmn = 0xFFFFFFFFu, lmx = 0u;
  for (int i = blockIdx.x * blockDim.x + tid; i < n; i += gridDim.x * blockDim.x){
    unsigned u = fmap(w[i]);
    lmn = min(lmn, u); lmx = max(lmx, u);
  }
  smn[tid] = lmn; smx[tid] = lmx;
  __syncthreads();
  for (int s = 128; s > 0; s >>= 1){
    if (tid < s){
      smn[tid] = min(smn[tid], smn[tid + s]);
      smx[tid] = max(smx[tid], smx[tid + s]);
    }
    __syncthreads();
  }
  if (tid == 0){ atomicMin(&mm[0], smn[0]); atomicMax(&mm[1], smx[0]); }
}

// ------------- fake-quant dequant + transpose + cast to bf16 ---------------
__global__ void dq_t(const float* __restrict__ w, bf16* __restrict__ wt,
                     int R, int C, const unsigned* __restrict__ mm){
  __shared__ float t[32][33];
  float xmin = funmap(mm[0]);
  float xmax = funmap(mm[1]);
  float scale = (xmax - xmin) / 255.0f;
  float denom = scale + 1e-8f;
  int ct = blockIdx.x * 32, rt = blockIdx.y * 32;
  int tx = threadIdx.x, ty = threadIdx.y;   // 32 x 8
#pragma unroll
  for (int p = 0; p < 4; ++p){
    int r = rt + p * 8 + ty;
    float x = w[(size_t)r * C + ct + tx];
    float q = rintf(fminf(fmaxf((x - xmin) / denom, 0.0f), 255.0f));
    t[p * 8 + ty][tx] = q * scale + xmin;
  }
  __syncthreads();
#pragma unroll
  for (int p = 0; p < 4; ++p){
    int c = p * 8 + ty;
    wt[(size_t)(ct + c) * R + rt + tx] = (bf16)t[tx][c];
  }
}

// ---------------- cast x (f32) -> bf16, vectorized x4 ----------------------
__global__ void cast_x(const float* __restrict__ x, bf16* __restrict__ xb, int n4){
  int i = blockIdx.x * 256 + threadIdx.x;
  if (i < n4){
    f32x4 v = *(const f32x4*)(x + (size_t)i * 4);
    bf16x4 o = { (bf16)v.x, (bf16)v.y, (bf16)v.z, (bf16)v.w };
    *(bf16x4*)(xb + (size_t)i * 4) = o;
  }
}

// ---------------- rope tables ----------------------------------------------
__global__ void sincos_k(float* __restrict__ sintab, float* __restrict__ costab){
  int idx = blockIdx.x * 256 + threadIdx.x;   // s*32 + i, 65536 total
  int i = idx & 31, s = idx >> 5;
  float invf = powf(10000.0f, -(float)i / 32.0f);
  float fr = (float)s * invf;
  sintab[idx] = sinf(fr);
  costab[idx] = cosf(fr);
}

// ------------- rope + reshape QKV(f32) -> Qr,Kr (B,H,S,D) bf16 -------------
// Q pre-scaled by (1/sqrt(D)) * log2(e) so attn uses exp2 directly.
__global__ void rope_qk(const float* __restrict__ qkv,
                        const float* __restrict__ sintab, const float* __restrict__ costab,
                        bf16* __restrict__ Qr, bf16* __restrict__ Kr){
  int idx = blockIdx.x * 256 + threadIdx.x;   // (bh*2048 + s)*32 + i
  int i  = idx & 31;
  int s  = (idx >> 5) & 2047;
  int bh = idx >> 16;
  int b = bh >> 4, h = bh & 15;
  const float QS = 0.18033688011f;   // 0.125 * log2(e)
  const float* row = qkv + (size_t)(b * 2048 + s) * 3072 + h * 64;
  float q1 = row[i],        q2 = row[32 + i];
  float k1 = row[1024 + i], k2 = row[1024 + 32 + i];
  float sn = sintab[s * 32 + i], cs = costab[s * 32 + i];
  size_t o = ((size_t)bh * 2048 + s) * 64 + i;
  Qr[o]      = (bf16)((q1 * cs - q2 * sn) * QS);
  Qr[o + 32] = (bf16)((q1 * sn + q2 * cs) * QS);
  Kr[o]      = (bf16)(k1 * cs - k2 * sn);
  Kr[o + 32] = (bf16)(k1 * sn + k2 * cs);
}

// ------------- V transpose: QKV(f32) -> Vt (B,H,D,S) bf16 ------------------
__global__ void vtrans(const float* __restrict__ qkv, bf16* __restrict__ Vt){
  __shared__ float t[64][65];
  int bh = blockIdx.x >> 5;
  int st = (blockIdx.x & 31) * 64;
  int b = bh >> 4, h = bh & 15;
  int tx = threadIdx.x & 63, ty4 = threadIdx.x >> 6;
#pragma unroll
  for (int p = 0; p < 16; ++p){
    int s = p * 4 + ty4;
    t[s][tx] = qkv[(size_t)(b * 2048 + st + s) * 3072 + 2048 + h * 64 + tx];
  }
  __syncthreads();
#pragma unroll
  for (int p = 0; p < 16; ++p){
    int d = p * 4 + ty4;
    Vt[((size_t)bh * 64 + d) * 2048 + st + tx] = (bf16)t[tx][d];
  }
}

// ---------------- bf16 MFMA GEMM, C = A * Bt^T (unchanged) -----------------
__global__ __launch_bounds__(256, 2) void gemm_bt(
    const bf16* __restrict__ A, const bf16* __restrict__ Bt,
    float* __restrict__ C, int M, int N, int K)
{
  __shared__ __align__(16) char lds[32768];
  int nbx = N >> 7;
  int bid = blockIdx.x;
  int nwg = gridDim.x;
  if ((nwg & 7) == 0){ int q = nwg >> 3; bid = (bid & 7) * q + (bid >> 3); }
  int row0 = (bid / nbx) << 7;
  int col0 = (bid % nbx) << 7;
  int tid = threadIdx.x, lane = tid & 63, wid = tid >> 6;
  int wr = (wid >> 1) * 64, wc = (wid & 1) * 64;
  int lr = lane & 15, g = lane >> 4;

  int aoff[2][4], boff[2][4];
#pragma unroll
  for (int kk = 0; kk < 2; ++kk){
#pragma unroll
    for (int m = 0; m < 4; ++m){
      int ra = wr + m * 16 + lr;
      aoff[kk][m] = ra * 128 + ((((kk * 4 + g) ^ ((ra >> 1) & 7))) << 4);
      int rb = wc + m * 16 + lr;
      boff[kk][m] = 16384 + rb * 128 + ((((kk * 4 + g) ^ ((rb >> 1) & 7))) << 4);
    }
  }

  const bf16* pA[4]; const bf16* pB[4]; int loff[4];
#pragma unroll
  for (int is = 0; is < 4; ++is){
    int f = is * 4096 + wid * 1024 + lane * 16;
    int r = f >> 7, c = (f >> 4) & 7;
    int cg = c ^ ((r >> 1) & 7);
    pA[is] = A  + (size_t)(row0 + r) * K + cg * 8;
    pB[is] = Bt + (size_t)(col0 + r) * K + cg * 8;
    loff[is] = is * 4096 + wid * 1024;
  }

  f32x4 acc[4][4] = {};
  for (int kt = 0; kt < K; kt += 64){
    __syncthreads();
#pragma unroll
    for (int is = 0; is < 4; ++is){
      GLDS16(pA[is] + kt, lds + loff[is]);
      GLDS16(pB[is] + kt, lds + 16384 + loff[is]);
    }
    __syncthreads();
#pragma unroll
    for (int kk = 0; kk < 2; ++kk){
      bf16x8 af[4], bfb[4];
#pragma unroll
      for (int m = 0; m < 4; ++m) af[m] = lds_frag(lds + aoff[kk][m]);
#pragma unroll
      for (int n = 0; n < 4; ++n) bfb[n] = lds_frag(lds + boff[kk][n]);
#pragma unroll
      for (int m = 0; m < 4; ++m)
#pragma unroll
        for (int n = 0; n < 4; ++n)
          acc[m][n] = MFMA16(af[m], bfb[n], acc[m][n]);
    }
  }

#pragma unroll
  for (int m = 0; m < 4; ++m){
    int row = row0 + wr + m * 16 + g * 4;
#pragma unroll
    for (int n = 0; n < 4; ++n){
      int col = col0 + wc + n * 16 + lr;
      float* cp = C + (size_t)row * N + col;
#pragma unroll
      for (int r = 0; r < 4; ++r)
        cp[(size_t)r * N] = acc[m][n][r];
    }
  }
}

// ---------------- flash attention, KV-split x4 + LDS merge -----------------
// grid: 2048 blocks (32 bh x 64 q-tiles); block = 4 waves sharing 32 queries,
// each wave owns a 512-key chunk with private online-softmax state.
// 32x32 MFMA, q = lane&31 per-lane softmax (tree reductions, defer-max THR=8
// in log2 domain), P fix-up via cvt_pk + v_permlane32_swap. End: m/l/O merge
// through LDS. launch_bounds(256,3): VGPR cap 170 (live ~150, NO spill);
// 3 blocks/CU (LDS 3x33.5KB=100KB) -> 24 waves/CU.
#define LOADK(KF, kvoff) do { _Pragma("unroll") \
    for (int t = 0; t < 4; ++t) \
      KF[t] = g_frag(Kb + (size_t)((kvoff) + l31) * 64 + t * 16 + hi8); } while(0)

#define LOADV(VF, kvoff) do { _Pragma("unroll") \
    for (int u = 0; u < 4; ++u) \
      VF[u] = g_frag(Vb + (size_t)((u & 1) * 32 + l31) * 2048 + (kvoff) + (u >> 1) * 16 + hi8); } while(0)

#define ATTN_TILE(KF, VF) do {                                               \
    f32x16 sc = {};                                                          \
    _Pragma("unroll")                                                        \
    for (int tt = 0; tt < 4; ++tt) sc = MFMA32(KF[tt], qf[tt], sc);          \
    float a0 = fmaxf(sc[0],sc[1]),  a1 = fmaxf(sc[2],sc[3]);                 \
    float a2 = fmaxf(sc[4],sc[5]),  a3 = fmaxf(sc[6],sc[7]);                 \
    float a4 = fmaxf(sc[8],sc[9]),  a5 = fmaxf(sc[10],sc[11]);               \
    float a6 = fmaxf(sc[12],sc[13]),a7 = fmaxf(sc[14],sc[15]);               \
    a0 = fmaxf(a0,a1); a2 = fmaxf(a2,a3); a4 = fmaxf(a4,a5); a6 = fmaxf(a6,a7);\
    a0 = fmaxf(a0,a2); a4 = fmaxf(a4,a6);                                    \
    float mt = fmaxf(a0,a4);                                                 \
    mt = fmaxf(mt, __shfl_xor(mt, 32));                                      \
    if (!__all(mt - mrun <= 8.0f)){                                          \
      float mn = fmaxf(mrun, mt);                                            \
      float cr = __builtin_amdgcn_exp2f(mrun - mn);                          \
      _Pragma("unroll")                                                      \
      for (int r = 0; r < 16; ++r){ o0[r] *= cr; o1[r] *= cr; }              \
      lrun *= cr; mrun = mn;                                                 \
    }                                                                        \
    _Pragma("unroll")                                                        \
    for (int r = 0; r < 16; ++r) sc[r] = __builtin_amdgcn_exp2f(sc[r] - mrun);\
    float s0 = (sc[0]+sc[1])+(sc[2]+sc[3]),   s1 = (sc[4]+sc[5])+(sc[6]+sc[7]);\
    float s2 = (sc[8]+sc[9])+(sc[10]+sc[11]), s3 = (sc[12]+sc[13])+(sc[14]+sc[15]);\
    float ps = (s0+s1)+(s2+s3);                                              \
    ps += __shfl_xor(ps, 32);                                                \
    lrun += ps;                                                              \
    _Pragma("unroll")                                                        \
    for (int kh = 0; kh < 2; ++kh){                                          \
      unsigned pa0 = pk_bf16(sc[kh*8+0], sc[kh*8+1]);                        \
      unsigned pa1 = pk_bf16(sc[kh*8+2], sc[kh*8+3]);                        \
      unsigned pb0 = pk_bf16(sc[kh*8+4], sc[kh*8+5]);                        \
      unsigned pb1 = pk_bf16(sc[kh*8+6], sc[kh*8+7]);                        \
      p32swap(pa0, pb0); p32swap(pa1, pb1);                                  \
      i32x4 wv = { (int)pa0, (int)pa1, (int)pb0, (int)pb1 };                 \
      bf16x8 pf = __builtin_bit_cast(bf16x8, wv);                            \
      o0 = MFMA32(VF[kh*2+0], pf, o0);                                       \
      o1 = MFMA32(VF[kh*2+1], pf, o1);                                       \
    }                                                                        \
  } while(0)

__global__ __launch_bounds__(256, 3) void attn_k(
    const bf16* __restrict__ Q, const bf16* __restrict__ K,
    const bf16* __restrict__ Vt, bf16* __restrict__ AO)
{
  __shared__ float mlds[4][2][32];                 // [wave][m/l][q]
  __shared__ float invL[32];
  __shared__ __align__(16) float Olds[4][64][32];  // [wave][d][q]  32 KB

  int bid = blockIdx.x;
  bid = (bid & 7) * 256 + (bid >> 3);     // XCD chunking: 4 heads per XCD
  int bh = bid >> 6;                      // 64 q-tiles per (b,h)
  int qblk = bid & 63;
  int b = bh >> 4, h = bh & 15;
  int tid = threadIdx.x, lane = tid & 63, wid = tid >> 6;
  int l31 = lane & 31, hi = lane >> 5, hi8 = hi * 8;
  int q0 = qblk * 32;

  const bf16* Qb = Q  + ((size_t)bh * 2048 + q0) * 64;
  const bf16* Kb = K  + (size_t)bh * 2048 * 64;
  const bf16* Vb = Vt + (size_t)bh * 64 * 2048;

  // Q B-frags: col = q (lane&31), d = t*16 + hi*8 + j (pre-scaled)
  bf16x8 qf[4];
#pragma unroll
  for (int t = 0; t < 4; ++t)
    qf[t] = g_frag(Qb + (size_t)l31 * 64 + t * 16 + hi8);

  f32x16 o0 = {}, o1 = {};     // O[d 0..31][q], O[d 32..63][q]
  float mrun = -1e30f, lrun = 0.0f;

  int kv0 = wid * 512;         // this wave's key chunk
  bf16x8 kfA[4], kfB[4], vf[4];
  LOADK(kfA, kv0);

  for (int t = 0; t < 16; t += 2){
    int kv = kv0 + t * 32;
    LOADV(vf, kv);
    LOADK(kfB, kv + 32);
    ATTN_TILE(kfA, vf);
    LOADV(vf, kv + 32);
    if (t < 14) LOADK(kfA, kv + 64);
    ATTN_TILE(kfB, vf);
  }

  // ---- cross-wave merge through LDS ----
  if (lane < 32){ mlds[wid][0][l31] = mrun; mlds[wid][1][l31] = lrun; }
  __syncthreads();
  float M = fmaxf(fmaxf(mlds[0][0][l31], mlds[1][0][l31]),
                  fmaxf(mlds[2][0][l31], mlds[3][0][l31]));
  float L = mlds[0][1][l31] * __builtin_amdgcn_exp2f(mlds[0][0][l31] - M)
          + mlds[1][1][l31] * __builtin_amdgcn_exp2f(mlds[1][0][l31] - M)
          + mlds[2][1][l31] * __builtin_amdgcn_exp2f(mlds[2][0][l31] - M)
          + mlds[3][1][l31] * __builtin_amdgcn_exp2f(mlds[3][0][l31] - M);
  if (wid == 0 && lane < 32) invL[l31] = 1.0f / L;
  float ew = __builtin_amdgcn_exp2f(mrun - M);
#pragma unroll
  for (int r = 0; r < 16; ++r){
    int d = 8 * (r >> 2) + 4 * hi + (r & 3);
    Olds[wid][d][l31]      = o0[r] * ew;
    Olds[wid][d + 32][l31] = o1[r] * ew;
  }
  __syncthreads();
  // merge + write: thread -> q = tid&31, d = (tid>>5)*8 .. +7
  int q = tid & 31, dbase = (tid >> 5) * 8;
  float iL = invL[q];
  bf16x8 ov;
#pragma unroll
  for (int j = 0; j < 8; ++j){
    int d = dbase + j;
    float s = ((Olds[0][d][q] + Olds[1][d][q]) + (Olds[2][d][q] + Olds[3][d][q]));
    ov[j] = (bf16)(s * iL);
  }
  *(bf16x8*)(AO + (size_t)(b * 2048 + q0 + q) * 1024 + h * 64 + dbase) = ov;
}

// ---------------------------------------------------------------------------
extern "C" void kernel_launch(void* const* d_in, const int* in_sizes, int n_in,
                              void* d_out, int out_size, void* d_ws, size_t ws_size,
                              hipStream_t stream) {
  const float* x     = (const float*)d_in[0];   // (2,2048,1024)
  const float* w_qkv = (const float*)d_in[1];   // (1024,3072)
  const float* w_out = (const float*)d_in[2];   // (1024,1024)
  float* out = (float*)d_out;                   // (2,2048,1024) f32

  char* ws = (char*)d_ws;
  const size_t MB = 1u << 20;
  unsigned* mm   = (unsigned*)(ws);              // 4 u32
  float* sintab  = (float*)(ws + 256);           // 256 KiB
  float* costab  = (float*)(ws + 256 + 262144);
  bf16* xb       = (bf16*)(ws + 1 * MB);         // 8 MiB
  bf16* wqkvT    = (bf16*)(ws + 9 * MB);         // 6 MiB  (3072 x 1024)
  bf16* woutT    = (bf16*)(ws + 15 * MB);        // 2 MiB  (1024 x 1024)
  float* qkvf    = (float*)(ws + 17 * MB);       // 48 MiB (4096 x 3072)
  bf16* Qr       = (bf16*)(ws + 65 * MB);        // 8 MiB  (32,2048,64)
  bf16* Kr       = (bf16*)(ws + 73 * MB);        // 8 MiB
  bf16* Vt       = (bf16*)(ws + 81 * MB);        // 8 MiB  (32,64,2048)
  bf16* AO       = (bf16*)(ws + 1 * MB);         // overlay on xb (dead after gemm1)

  init_mm<<<1, 64, 0, stream>>>(mm);
  minmax_k<<<512, 256, 0, stream>>>(w_qkv, 1024 * 3072, mm);
  minmax_k<<<512, 256, 0, stream>>>(w_out, 1024 * 1024, mm + 2);
  sincos_k<<<256, 256, 0, stream>>>(sintab, costab);
  cast_x<<<4096, 256, 0, stream>>>(x, xb, 4194304 / 4);
  dq_t<<<dim3(96, 32), dim3(32, 8), 0, stream>>>(w_qkv, wqkvT, 1024, 3072, mm);
  dq_t<<<dim3(32, 32), dim3(32, 8), 0, stream>>>(w_out, woutT, 1024, 1024, mm + 2);
  gemm_bt<<<768, 256, 0, stream>>>(xb, wqkvT, qkvf, 4096, 3072, 1024);
  rope_qk<<<8192, 256, 0, stream>>>(qkvf, sintab, costab, Qr, Kr);
  vtrans<<<1024, 256, 0, stream>>>(qkvf, Vt);
  attn_k<<<2048, 256, 0, stream>>>(Qr, Kr, Vt, AO);
  gemm_bt<<<256, 256, 0, stream>>>(AO, woutT, out, 4096, 1024, 1024);

  (void)in_sizes; (void)n_in; (void)out_size; (void)ws_size;
}

// Round 6
// 171.898 us; speedup vs baseline: 1.5061x; 1.3962x over previous
//
#include <hip/hip_runtime.h>
#include <hip/hip_bf16.h>

typedef __bf16 bf16;
typedef bf16  bf16x8 __attribute__((ext_vector_type(8)));
typedef bf16  bf16x4 __attribute__((ext_vector_type(4)));
typedef bf16  bf16x2 __attribute__((ext_vector_type(2)));
typedef float f32x4  __attribute__((ext_vector_type(4)));
typedef float f32x16 __attribute__((ext_vector_type(16)));
typedef int   i32x4  __attribute__((ext_vector_type(4)));

#define MFMA16(a,b,c) __builtin_amdgcn_mfma_f32_16x16x32_bf16((a),(b),(c),0,0,0)
#define MFMA32(a,b,c) __builtin_amdgcn_mfma_f32_32x32x16_bf16((a),(b),(c),0,0,0)

#define GLDS16(gp, lp) __builtin_amdgcn_global_load_lds( \
    (const __attribute__((address_space(1))) void*)(void*)(gp), \
    (__attribute__((address_space(3))) void*)(lp), 16, 0, 0)

static __device__ __forceinline__ bf16x8 lds_frag(const char* p){
  i32x4 v = *(const i32x4*)p;
  return __builtin_bit_cast(bf16x8, v);
}
static __device__ __forceinline__ bf16x8 g_frag(const bf16* p){
  i32x4 v = *(const i32x4*)p;
  return __builtin_bit_cast(bf16x8, v);
}
static __device__ __forceinline__ unsigned pk_bf16(float a, float b){
  bf16x2 v = { (bf16)a, (bf16)b };
  return __builtin_bit_cast(unsigned, v);
}
// swap upper 32 lanes of a with lower 32 lanes of b (gfx950)
static __device__ __forceinline__ void p32swap(unsigned &a, unsigned &b){
  asm("v_permlane32_swap_b32 %0, %1" : "+v"(a), "+v"(b));
}

// ---------------- min/max reduction (order-independent -> deterministic) ---
__device__ __forceinline__ unsigned fmap(float f){
  unsigned u = __float_as_uint(f);
  return (u & 0x80000000u) ? ~u : (u | 0x80000000u);
}
__device__ __forceinline__ float funmap(unsigned m){
  unsigned u = (m & 0x80000000u) ? (m & 0x7FFFFFFFu) : ~m;
  return __uint_as_float(u);
}

__global__ void init_mm(unsigned* mm){
  if (threadIdx.x == 0){
    mm[0] = 0xFFFFFFFFu; mm[1] = 0u;   // w_qkv min,max (mapped)
    mm[2] = 0xFFFFFFFFu; mm[3] = 0u;   // w_out min,max
  }
}

__global__ void minmax_k(const float* __restrict__ w, int n, unsigned* __restrict__ mm){
  __shared__ unsigned smn[256], smx[256];
  int tid = threadIdx.x;
  unsigned lmn = 0xFFFFFFFFu, lmx = 0u;
  for (int i = blockIdx.x * blockDim.x + tid; i < n; i += gridDim.x * blockDim.x){
    unsigned u = fmap(w[i]);
    lmn = min(lmn, u); lmx = max(lmx, u);
  }
  smn[tid] = lmn; smx[tid] = lmx;
  __syncthreads();
  for (int s = 128; s > 0; s >>= 1){
    if (tid < s){
      smn[tid] = min(smn[tid], smn[tid + s]);
      smx[tid] = max(smx[tid], smx[tid + s]);
    }
    __syncthreads();
  }
  if (tid == 0){ atomicMin(&mm[0], smn[0]); atomicMax(&mm[1], smx[0]); }
}

// ------------- fake-quant dequant + transpose + cast to bf16 ---------------
__global__ void dq_t(const float* __restrict__ w, bf16* __restrict__ wt,
                     int R, int C, const unsigned* __restrict__ mm){
  __shared__ float t[32][33];
  float xmin = funmap(mm[0]);
  float xmax = funmap(mm[1]);
  float scale = (xmax - xmin) / 255.0f;
  float denom = scale + 1e-8f;
  int ct = blockIdx.x * 32, rt = blockIdx.y * 32;
  int tx = threadIdx.x, ty = threadIdx.y;   // 32 x 8
#pragma unroll
  for (int p = 0; p < 4; ++p){
    int r = rt + p * 8 + ty;
    float x = w[(size_t)r * C + ct + tx];
    float q = rintf(fminf(fmaxf((x - xmin) / denom, 0.0f), 255.0f));
    t[p * 8 + ty][tx] = q * scale + xmin;
  }
  __syncthreads();
#pragma unroll
  for (int p = 0; p < 4; ++p){
    int c = p * 8 + ty;
    wt[(size_t)(ct + c) * R + rt + tx] = (bf16)t[tx][c];
  }
}

// ---------------- cast x (f32) -> bf16, vectorized x4 ----------------------
__global__ void cast_x(const float* __restrict__ x, bf16* __restrict__ xb, int n4){
  int i = blockIdx.x * 256 + threadIdx.x;
  if (i < n4){
    f32x4 v = *(const f32x4*)(x + (size_t)i * 4);
    bf16x4 o = { (bf16)v.x, (bf16)v.y, (bf16)v.z, (bf16)v.w };
    *(bf16x4*)(xb + (size_t)i * 4) = o;
  }
}

// ---------------- rope tables ----------------------------------------------
__global__ void sincos_k(float* __restrict__ sintab, float* __restrict__ costab){
  int idx = blockIdx.x * 256 + threadIdx.x;   // s*32 + i, 65536 total
  int i = idx & 31, s = idx >> 5;
  float invf = powf(10000.0f, -(float)i / 32.0f);
  float fr = (float)s * invf;
  sintab[idx] = sinf(fr);
  costab[idx] = cosf(fr);
}

// ------------- rope + reshape QKV(f32) -> Qr,Kr (B,H,S,D) bf16 -------------
// Q pre-scaled by (1/sqrt(D)) * log2(e) so attn uses exp2 directly.
__global__ void rope_qk(const float* __restrict__ qkv,
                        const float* __restrict__ sintab, const float* __restrict__ costab,
                        bf16* __restrict__ Qr, bf16* __restrict__ Kr){
  int idx = blockIdx.x * 256 + threadIdx.x;   // (bh*2048 + s)*32 + i
  int i  = idx & 31;
  int s  = (idx >> 5) & 2047;
  int bh = idx >> 16;
  int b = bh >> 4, h = bh & 15;
  const float QS = 0.18033688011f;   // 0.125 * log2(e)
  const float* row = qkv + (size_t)(b * 2048 + s) * 3072 + h * 64;
  float q1 = row[i],        q2 = row[32 + i];
  float k1 = row[1024 + i], k2 = row[1024 + 32 + i];
  float sn = sintab[s * 32 + i], cs = costab[s * 32 + i];
  size_t o = ((size_t)bh * 2048 + s) * 64 + i;
  Qr[o]      = (bf16)((q1 * cs - q2 * sn) * QS);
  Qr[o + 32] = (bf16)((q1 * sn + q2 * cs) * QS);
  Kr[o]      = (bf16)(k1 * cs - k2 * sn);
  Kr[o + 32] = (bf16)(k1 * sn + k2 * cs);
}

// ------------- V transpose: QKV(f32) -> Vt (B,H,D,S) bf16 ------------------
__global__ void vtrans(const float* __restrict__ qkv, bf16* __restrict__ Vt){
  __shared__ float t[64][65];
  int bh = blockIdx.x >> 5;
  int st = (blockIdx.x & 31) * 64;
  int b = bh >> 4, h = bh & 15;
  int tx = threadIdx.x & 63, ty4 = threadIdx.x >> 6;
#pragma unroll
  for (int p = 0; p < 16; ++p){
    int s = p * 4 + ty4;
    t[s][tx] = qkv[(size_t)(b * 2048 + st + s) * 3072 + 2048 + h * 64 + tx];
  }
  __syncthreads();
#pragma unroll
  for (int p = 0; p < 16; ++p){
    int d = p * 4 + ty4;
    Vt[((size_t)bh * 64 + d) * 2048 + st + tx] = (bf16)t[tx][d];
  }
}

// ---------------- bf16 MFMA GEMM, C = A * Bt^T (unchanged) -----------------
__global__ __launch_bounds__(256, 2) void gemm_bt(
    const bf16* __restrict__ A, const bf16* __restrict__ Bt,
    float* __restrict__ C, int M, int N, int K)
{
  __shared__ __align__(16) char lds[32768];
  int nbx = N >> 7;
  int bid = blockIdx.x;
  int nwg = gridDim.x;
  if ((nwg & 7) == 0){ int q = nwg >> 3; bid = (bid & 7) * q + (bid >> 3); }
  int row0 = (bid / nbx) << 7;
  int col0 = (bid % nbx) << 7;
  int tid = threadIdx.x, lane = tid & 63, wid = tid >> 6;
  int wr = (wid >> 1) * 64, wc = (wid & 1) * 64;
  int lr = lane & 15, g = lane >> 4;

  int aoff[2][4], boff[2][4];
#pragma unroll
  for (int kk = 0; kk < 2; ++kk){
#pragma unroll
    for (int m = 0; m < 4; ++m){
      int ra = wr + m * 16 + lr;
      aoff[kk][m] = ra * 128 + ((((kk * 4 + g) ^ ((ra >> 1) & 7))) << 4);
      int rb = wc + m * 16 + lr;
      boff[kk][m] = 16384 + rb * 128 + ((((kk * 4 + g) ^ ((rb >> 1) & 7))) << 4);
    }
  }

  const bf16* pA[4]; const bf16* pB[4]; int loff[4];
#pragma unroll
  for (int is = 0; is < 4; ++is){
    int f = is * 4096 + wid * 1024 + lane * 16;
    int r = f >> 7, c = (f >> 4) & 7;
    int cg = c ^ ((r >> 1) & 7);
    pA[is] = A  + (size_t)(row0 + r) * K + cg * 8;
    pB[is] = Bt + (size_t)(col0 + r) * K + cg * 8;
    loff[is] = is * 4096 + wid * 1024;
  }

  f32x4 acc[4][4] = {};
  for (int kt = 0; kt < K; kt += 64){
    __syncthreads();
#pragma unroll
    for (int is = 0; is < 4; ++is){
      GLDS16(pA[is] + kt, lds + loff[is]);
      GLDS16(pB[is] + kt, lds + 16384 + loff[is]);
    }
    __syncthreads();
#pragma unroll
    for (int kk = 0; kk < 2; ++kk){
      bf16x8 af[4], bfb[4];
#pragma unroll
      for (int m = 0; m < 4; ++m) af[m] = lds_frag(lds + aoff[kk][m]);
#pragma unroll
      for (int n = 0; n < 4; ++n) bfb[n] = lds_frag(lds + boff[kk][n]);
#pragma unroll
      for (int m = 0; m < 4; ++m)
#pragma unroll
        for (int n = 0; n < 4; ++n)
          acc[m][n] = MFMA16(af[m], bfb[n], acc[m][n]);
    }
  }

#pragma unroll
  for (int m = 0; m < 4; ++m){
    int row = row0 + wr + m * 16 + g * 4;
#pragma unroll
    for (int n = 0; n < 4; ++n){
      int col = col0 + wc + n * 16 + lr;
      float* cp = C + (size_t)row * N + col;
#pragma unroll
      for (int r = 0; r < 4; ++r)
        cp[(size_t)r * N] = acc[m][n][r];
    }
  }
}

// ---------------- flash attention v6: LDS-staged K/V, no KV-split ----------
// grid: 512 blocks (32 bh x 16 qblk); block = 4 waves; wave owns 32 queries,
// sweeps ALL 2048 keys. K/V staged per 64-key chunk via global_load_lds into
// 16KB LDS (chunk-XOR swizzle both sides, gemm_bt pattern) shared by the 4
// waves -> load latency decoupled from registers (the R3-R5 serialization
// killer). Softmax per-lane with lazy cross-half max (shfl only on rescale
// path) + per-half lrun partials (one shfl at end). No cross-wave merge.
__global__ __launch_bounds__(256, 2) void attn_k(
    const bf16* __restrict__ Q, const bf16* __restrict__ K,
    const bf16* __restrict__ Vt, bf16* __restrict__ AO)
{
  __shared__ __align__(16) char kl[8192];   // 64 keys x 128B, chunk-swizzled
  __shared__ __align__(16) char vl[8192];   // 64 d    x 128B (keys along row)

  int bid = blockIdx.x;
  bid = (bid & 7) * 64 + (bid >> 3);        // XCD chunking: 4 heads per XCD
  int bh = bid >> 4, qblk = bid & 15;
  int b = bh >> 4, h = bh & 15;
  int tid = threadIdx.x, lane = tid & 63, wid = tid >> 6;
  int l31 = lane & 31, hi = lane >> 5, hi8 = hi * 8;
  int q0 = qblk * 128 + wid * 32;

  const bf16* Qb = Q  + ((size_t)bh * 2048 + q0) * 64;
  const bf16* Kb = K  + (size_t)bh * 2048 * 64;
  const bf16* Vb = Vt + (size_t)bh * 64 * 2048;

  // Q B-frags: col = q (lane&31), d = t*16 + hi*8 + j (pre-scaled, log2 dom.)
  bf16x8 qf[4];
#pragma unroll
  for (int t = 0; t < 4; ++t)
    qf[t] = g_frag(Qb + (size_t)l31 * 64 + t * 16 + hi8);

  // staging sources (pre-swizzled chunks -> linear LDS dest), 2 issues each
  const bf16* pKs[2]; const bf16* pVs[2]; int ldo[2];
#pragma unroll
  for (int is = 0; is < 2; ++is){
    int f = wid * 2048 + is * 1024 + lane * 16;   // byte index in 8KB tile
    int r = f >> 7;                                // row (key for K, d for V)
    int cg = ((f >> 4) & 7) ^ (r & 7);             // swizzled 16B chunk
    pKs[is] = Kb + (size_t)r * 64 + cg * 8;        // + kv0*64 per chunk
    pVs[is] = Vb + (size_t)r * 2048 + cg * 8;      // + kv0 per chunk
    ldo[is] = wid * 2048 + is * 1024;              // wave-uniform LDS base
  }

  f32x16 o0 = {}, o1 = {};     // O[d 0..31][q], O[d 32..63][q]
  float mrun = -1e30f, lrun = 0.0f;

  for (int c = 0; c < 32; ++c){
    int kv0 = c * 64;
    __syncthreads();           // prior chunk's reads complete before overwrite
#pragma unroll
    for (int is = 0; is < 2; ++is){
      GLDS16(pKs[is] + (size_t)kv0 * 64, kl + ldo[is]);
      GLDS16(pVs[is] + kv0,              vl + ldo[is]);
    }
    __syncthreads();           // compiler drains vmcnt before barrier

#pragma unroll
    for (int kk = 0; kk < 2; ++kk){
      // K A-frags: row = key = kk*32 + l31, d-slice chunk = 2t+hi (swizzled)
      int krow = kk * 32 + l31;
      bf16x8 kf[4], vfr[4];
#pragma unroll
      for (int t = 0; t < 4; ++t)
        kf[t] = lds_frag(kl + krow * 128 + ((((2 * t + hi) ^ (krow & 7))) << 4));
      // V A-frags: row = d = (u&1)*32 + l31, key-chunk = kk*4 + (u>>1)*2 + hi
#pragma unroll
      for (int u = 0; u < 4; ++u){
        int d = (u & 1) * 32 + l31;
        vfr[u] = lds_frag(vl + d * 128 +
                          ((((kk * 4) + ((u >> 1) * 2) + hi) ^ (d & 7)) << 4));
      }
      f32x16 sc = {};
#pragma unroll
      for (int t = 0; t < 4; ++t) sc = MFMA32(kf[t], qf[t], sc);

      // lazy max: per-half-lane tree max; cross-half shfl only when rescaling
      float a0 = fmaxf(sc[0], sc[1]),   a1 = fmaxf(sc[2], sc[3]);
      float a2 = fmaxf(sc[4], sc[5]),   a3 = fmaxf(sc[6], sc[7]);
      float a4 = fmaxf(sc[8], sc[9]),   a5 = fmaxf(sc[10], sc[11]);
      float a6 = fmaxf(sc[12], sc[13]), a7 = fmaxf(sc[14], sc[15]);
      a0 = fmaxf(a0, a1); a2 = fmaxf(a2, a3);
      a4 = fmaxf(a4, a5); a6 = fmaxf(a6, a7);
      float mt = fmaxf(fmaxf(a0, a2), fmaxf(a4, a6));
      if (!__all(mt - mrun <= 8.0f)){
        mt = fmaxf(mt, __shfl_xor(mt, 32));
        float mn = fmaxf(mrun, mt);
        float cr = __builtin_amdgcn_exp2f(mrun - mn);
#pragma unroll
        for (int r = 0; r < 16; ++r){ o0[r] *= cr; o1[r] *= cr; }
        lrun *= cr; mrun = mn;
      }
#pragma unroll
      for (int r = 0; r < 16; ++r) sc[r] = __builtin_amdgcn_exp2f(sc[r] - mrun);
      float s0 = (sc[0] + sc[1]) + (sc[2] + sc[3]);
      float s1 = (sc[4] + sc[5]) + (sc[6] + sc[7]);
      float s2 = (sc[8] + sc[9]) + (sc[10] + sc[11]);
      float s3 = (sc[12] + sc[13]) + (sc[14] + sc[15]);
      lrun += (s0 + s1) + (s2 + s3);     // per-half partial; combined at end

      // pack P -> B-frag layout (cvt_pk + permlane32_swap), then PV
#pragma unroll
      for (int kh = 0; kh < 2; ++kh){
        unsigned pa0 = pk_bf16(sc[kh * 8 + 0], sc[kh * 8 + 1]);
        unsigned pa1 = pk_bf16(sc[kh * 8 + 2], sc[kh * 8 + 3]);
        unsigned pb0 = pk_bf16(sc[kh * 8 + 4], sc[kh * 8 + 5]);
        unsigned pb1 = pk_bf16(sc[kh * 8 + 6], sc[kh * 8 + 7]);
        p32swap(pa0, pb0); p32swap(pa1, pb1);
        i32x4 wv = { (int)pa0, (int)pa1, (int)pb0, (int)pb1 };
        bf16x8 pf = __builtin_bit_cast(bf16x8, wv);
        o0 = MFMA32(vfr[kh * 2 + 0], pf, o0);
        o1 = MFMA32(vfr[kh * 2 + 1], pf, o1);
      }
    }
  }

  // epilogue: combine half-lane l partials; o reg r -> d = 8*(r>>2)+4*hi+(r&3)
  float lt = lrun + __shfl_xor(lrun, 32);
  float inv = 1.0f / lt;
  size_t row = (size_t)b * 2048 + q0 + l31;
  bf16* op = AO + row * 1024 + h * 64 + hi * 4;
#pragma unroll
  for (int qd = 0; qd < 4; ++qd){
    bf16x4 w0 = { (bf16)(o0[qd*4+0]*inv), (bf16)(o0[qd*4+1]*inv),
                  (bf16)(o0[qd*4+2]*inv), (bf16)(o0[qd*4+3]*inv) };
    *(bf16x4*)(op + qd * 8) = w0;
    bf16x4 w1 = { (bf16)(o1[qd*4+0]*inv), (bf16)(o1[qd*4+1]*inv),
                  (bf16)(o1[qd*4+2]*inv), (bf16)(o1[qd*4+3]*inv) };
    *(bf16x4*)(op + 32 + qd * 8) = w1;
  }
}

// ---------------------------------------------------------------------------
extern "C" void kernel_launch(void* const* d_in, const int* in_sizes, int n_in,
                              void* d_out, int out_size, void* d_ws, size_t ws_size,
                              hipStream_t stream) {
  const float* x     = (const float*)d_in[0];   // (2,2048,1024)
  const float* w_qkv = (const float*)d_in[1];   // (1024,3072)
  const float* w_out = (const float*)d_in[2];   // (1024,1024)
  float* out = (float*)d_out;                   // (2,2048,1024) f32

  char* ws = (char*)d_ws;
  const size_t MB = 1u << 20;
  unsigned* mm   = (unsigned*)(ws);              // 4 u32
  float* sintab  = (float*)(ws + 256);           // 256 KiB
  float* costab  = (float*)(ws + 256 + 262144);
  bf16* xb       = (bf16*)(ws + 1 * MB);         // 8 MiB
  bf16* wqkvT    = (bf16*)(ws + 9 * MB);         // 6 MiB  (3072 x 1024)
  bf16* woutT    = (bf16*)(ws + 15 * MB);        // 2 MiB  (1024 x 1024)
  float* qkvf    = (float*)(ws + 17 * MB);       // 48 MiB (4096 x 3072)
  bf16* Qr       = (bf16*)(ws + 65 * MB);        // 8 MiB  (32,2048,64)
  bf16* Kr       = (bf16*)(ws + 73 * MB);        // 8 MiB
  bf16* Vt       = (bf16*)(ws + 81 * MB);        // 8 MiB  (32,64,2048)
  bf16* AO       = (bf16*)(ws + 1 * MB);         // overlay on xb (dead after gemm1)

  init_mm<<<1, 64, 0, stream>>>(mm);
  minmax_k<<<512, 256, 0, stream>>>(w_qkv, 1024 * 3072, mm);
  minmax_k<<<512, 256, 0, stream>>>(w_out, 1024 * 1024, mm + 2);
  sincos_k<<<256, 256, 0, stream>>>(sintab, costab);
  cast_x<<<4096, 256, 0, stream>>>(x, xb, 4194304 / 4);
  dq_t<<<dim3(96, 32), dim3(32, 8), 0, stream>>>(w_qkv, wqkvT, 1024, 3072, mm);
  dq_t<<<dim3(32, 32), dim3(32, 8), 0, stream>>>(w_out, woutT, 1024, 1024, mm + 2);
  gemm_bt<<<768, 256, 0, stream>>>(xb, wqkvT, qkvf, 4096, 3072, 1024);
  rope_qk<<<8192, 256, 0, stream>>>(qkvf, sintab, costab, Qr, Kr);
  vtrans<<<1024, 256, 0, stream>>>(qkvf, Vt);
  attn_k<<<512, 256, 0, stream>>>(Qr, Kr, Vt, AO);
  gemm_bt<<<256, 256, 0, stream>>>(AO, woutT, out, 4096, 1024, 1024);

  (void)in_sizes; (void)n_in; (void)out_size; (void)ws_size;
}

// Round 7
// 162.988 us; speedup vs baseline: 1.5884x; 1.0547x over previous
//
#include <hip/hip_runtime.h>
#include <hip/hip_bf16.h>

typedef __bf16 bf16;
typedef bf16  bf16x8 __attribute__((ext_vector_type(8)));
typedef bf16  bf16x4 __attribute__((ext_vector_type(4)));
typedef bf16  bf16x2 __attribute__((ext_vector_type(2)));
typedef float f32x4  __attribute__((ext_vector_type(4)));
typedef float f32x16 __attribute__((ext_vector_type(16)));
typedef int   i32x4  __attribute__((ext_vector_type(4)));

#define MFMA16(a,b,c) __builtin_amdgcn_mfma_f32_16x16x32_bf16((a),(b),(c),0,0,0)
#define MFMA32(a,b,c) __builtin_amdgcn_mfma_f32_32x32x16_bf16((a),(b),(c),0,0,0)

#define GLDS16(gp, lp) __builtin_amdgcn_global_load_lds( \
    (const __attribute__((address_space(1))) void*)(void*)(gp), \
    (__attribute__((address_space(3))) void*)(lp), 16, 0, 0)

static __device__ __forceinline__ bf16x8 lds_frag(const char* p){
  i32x4 v = *(const i32x4*)p;
  return __builtin_bit_cast(bf16x8, v);
}
static __device__ __forceinline__ bf16x8 g_frag(const bf16* p){
  i32x4 v = *(const i32x4*)p;
  return __builtin_bit_cast(bf16x8, v);
}
static __device__ __forceinline__ unsigned pk_bf16(float a, float b){
  bf16x2 v = { (bf16)a, (bf16)b };
  return __builtin_bit_cast(unsigned, v);
}
// swap upper 32 lanes of a with lower 32 lanes of b (gfx950)
static __device__ __forceinline__ void p32swap(unsigned &a, unsigned &b){
  asm("v_permlane32_swap_b32 %0, %1" : "+v"(a), "+v"(b));
}

// ---------------- min/max reduction (order-independent -> deterministic) ---
__device__ __forceinline__ unsigned fmap(float f){
  unsigned u = __float_as_uint(f);
  return (u & 0x80000000u) ? ~u : (u | 0x80000000u);
}
__device__ __forceinline__ float funmap(unsigned m){
  unsigned u = (m & 0x80000000u) ? (m & 0x7FFFFFFFu) : ~m;
  return __uint_as_float(u);
}

__global__ void init_mm(unsigned* mm){
  if (threadIdx.x == 0){
    mm[0] = 0xFFFFFFFFu; mm[1] = 0u;   // w_qkv min,max (mapped)
    mm[2] = 0xFFFFFFFFu; mm[3] = 0u;   // w_out min,max
  }
}

__global__ void minmax_k(const float* __restrict__ w, int n, unsigned* __restrict__ mm){
  __shared__ unsigned smn[256], smx[256];
  int tid = threadIdx.x;
  unsigned lmn = 0xFFFFFFFFu, lmx = 0u;
  for (int i = blockIdx.x * blockDim.x + tid; i < n; i += gridDim.x * blockDim.x){
    unsigned u = fmap(w[i]);
    lmn = min(lmn, u); lmx = max(lmx, u);
  }
  smn[tid] = lmn; smx[tid] = lmx;
  __syncthreads();
  for (int s = 128; s > 0; s >>= 1){
    if (tid < s){
      smn[tid] = min(smn[tid], smn[tid + s]);
      smx[tid] = max(smx[tid], smx[tid + s]);
    }
    __syncthreads();
  }
  if (tid == 0){ atomicMin(&mm[0], smn[0]); atomicMax(&mm[1], smx[0]); }
}

// ------------- fake-quant dequant + transpose + cast to bf16 ---------------
__global__ void dq_t(const float* __restrict__ w, bf16* __restrict__ wt,
                     int R, int C, const unsigned* __restrict__ mm){
  __shared__ float t[32][33];
  float xmin = funmap(mm[0]);
  float xmax = funmap(mm[1]);
  float scale = (xmax - xmin) / 255.0f;
  float denom = scale + 1e-8f;
  int ct = blockIdx.x * 32, rt = blockIdx.y * 32;
  int tx = threadIdx.x, ty = threadIdx.y;   // 32 x 8
#pragma unroll
  for (int p = 0; p < 4; ++p){
    int r = rt + p * 8 + ty;
    float x = w[(size_t)r * C + ct + tx];
    float q = rintf(fminf(fmaxf((x - xmin) / denom, 0.0f), 255.0f));
    t[p * 8 + ty][tx] = q * scale + xmin;
  }
  __syncthreads();
#pragma unroll
  for (int p = 0; p < 4; ++p){
    int c = p * 8 + ty;
    wt[(size_t)(ct + c) * R + rt + tx] = (bf16)t[tx][c];
  }
}

// ---------------- cast x (f32) -> bf16, vectorized x4 ----------------------
__global__ void cast_x(const float* __restrict__ x, bf16* __restrict__ xb, int n4){
  int i = blockIdx.x * 256 + threadIdx.x;
  if (i < n4){
    f32x4 v = *(const f32x4*)(x + (size_t)i * 4);
    bf16x4 o = { (bf16)v.x, (bf16)v.y, (bf16)v.z, (bf16)v.w };
    *(bf16x4*)(xb + (size_t)i * 4) = o;
  }
}

// ---------------- rope table: packed (cos, sin) ----------------------------
__global__ void sincos_k(float2* __restrict__ sctab){
  int idx = blockIdx.x * 256 + threadIdx.x;   // s*32 + i, 65536 total
  int i = idx & 31, s = idx >> 5;
  float invf = powf(10000.0f, -(float)i / 32.0f);
  float fr = (float)s * invf;
  float2 cs; cs.x = cosf(fr); cs.y = sinf(fr);
  sctab[idx] = cs;
}

// ------------- V transpose: Vraw (B,H,S,D) bf16 -> Vt (B,H,D,S) bf16 -------
__global__ void vtrans_b(const bf16* __restrict__ Vraw, bf16* __restrict__ Vt){
  __shared__ float t[64][65];
  int bh = blockIdx.x >> 5;
  int st = (blockIdx.x & 31) * 64;
  int tx = threadIdx.x & 63, ty4 = threadIdx.x >> 6;
#pragma unroll
  for (int p = 0; p < 16; ++p){
    int s = p * 4 + ty4;
    t[s][tx] = (float)Vraw[((size_t)bh * 2048 + st + s) * 64 + tx];
  }
  __syncthreads();
#pragma unroll
  for (int p = 0; p < 16; ++p){
    int d = p * 4 + ty4;
    Vt[((size_t)bh * 64 + d) * 2048 + st + tx] = (bf16)t[tx][d];
  }
}

// ---------------- bf16 MFMA GEMM, C = A * Bt^T (for out-proj) --------------
__global__ __launch_bounds__(256, 2) void gemm_bt(
    const bf16* __restrict__ A, const bf16* __restrict__ Bt,
    float* __restrict__ C, int M, int N, int K)
{
  __shared__ __align__(16) char lds[32768];
  int nbx = N >> 7;
  int bid = blockIdx.x;
  int nwg = gridDim.x;
  if ((nwg & 7) == 0){ int q = nwg >> 3; bid = (bid & 7) * q + (bid >> 3); }
  int row0 = (bid / nbx) << 7;
  int col0 = (bid % nbx) << 7;
  int tid = threadIdx.x, lane = tid & 63, wid = tid >> 6;
  int wr = (wid >> 1) * 64, wc = (wid & 1) * 64;
  int lr = lane & 15, g = lane >> 4;

  int aoff[2][4], boff[2][4];
#pragma unroll
  for (int kk = 0; kk < 2; ++kk){
#pragma unroll
    for (int m = 0; m < 4; ++m){
      int ra = wr + m * 16 + lr;
      aoff[kk][m] = ra * 128 + ((((kk * 4 + g) ^ ((ra >> 1) & 7))) << 4);
      int rb = wc + m * 16 + lr;
      boff[kk][m] = 16384 + rb * 128 + ((((kk * 4 + g) ^ ((rb >> 1) & 7))) << 4);
    }
  }

  const bf16* pA[4]; const bf16* pB[4]; int loff[4];
#pragma unroll
  for (int is = 0; is < 4; ++is){
    int f = is * 4096 + wid * 1024 + lane * 16;
    int r = f >> 7, c = (f >> 4) & 7;
    int cg = c ^ ((r >> 1) & 7);
    pA[is] = A  + (size_t)(row0 + r) * K + cg * 8;
    pB[is] = Bt + (size_t)(col0 + r) * K + cg * 8;
    loff[is] = is * 4096 + wid * 1024;
  }

  f32x4 acc[4][4] = {};
  for (int kt = 0; kt < K; kt += 64){
    __syncthreads();
#pragma unroll
    for (int is = 0; is < 4; ++is){
      GLDS16(pA[is] + kt, lds + loff[is]);
      GLDS16(pB[is] + kt, lds + 16384 + loff[is]);
    }
    __syncthreads();
#pragma unroll
    for (int kk = 0; kk < 2; ++kk){
      bf16x8 af[4], bfb[4];
#pragma unroll
      for (int m = 0; m < 4; ++m) af[m] = lds_frag(lds + aoff[kk][m]);
#pragma unroll
      for (int n = 0; n < 4; ++n) bfb[n] = lds_frag(lds + boff[kk][n]);
#pragma unroll
      for (int m = 0; m < 4; ++m)
#pragma unroll
        for (int n = 0; n < 4; ++n)
          acc[m][n] = MFMA16(af[m], bfb[n], acc[m][n]);
    }
  }

#pragma unroll
  for (int m = 0; m < 4; ++m){
    int row = row0 + wr + m * 16 + g * 4;
#pragma unroll
    for (int n = 0; n < 4; ++n){
      int col = col0 + wc + n * 16 + lr;
      float* cp = C + (size_t)row * N + col;
#pragma unroll
      for (int r = 0; r < 4; ++r)
        cp[(size_t)r * N] = acc[m][n][r];
    }
  }
}

// ------- QKV GEMM with fused RoPE/split epilogue ---------------------------
// C-tile cols map to (sect,h,d): head = col/64, sect = head>>4 (q/k/v).
// RoPE pair (d, d+32) lives in (acc[m][n], acc[m][n+2]) of the SAME thread.
// Writes Qr (RoPE, pre-scaled by 0.125*log2e), Kr (RoPE), Vraw (plain bf16).
__global__ __launch_bounds__(256, 2) void gemm_qkv(
    const bf16* __restrict__ A, const bf16* __restrict__ Bt,
    const float2* __restrict__ sctab,
    bf16* __restrict__ Qr, bf16* __restrict__ Kr, bf16* __restrict__ Vraw,
    int M, int N, int K)
{
  __shared__ __align__(16) char lds[32768];
  int nbx = N >> 7;
  int bid = blockIdx.x;
  int nwg = gridDim.x;
  if ((nwg & 7) == 0){ int q = nwg >> 3; bid = (bid & 7) * q + (bid >> 3); }
  int row0 = (bid / nbx) << 7;
  int col0 = (bid % nbx) << 7;
  int tid = threadIdx.x, lane = tid & 63, wid = tid >> 6;
  int wr = (wid >> 1) * 64, wc = (wid & 1) * 64;
  int lr = lane & 15, g = lane >> 4;

  int aoff[2][4], boff[2][4];
#pragma unroll
  for (int kk = 0; kk < 2; ++kk){
#pragma unroll
    for (int m = 0; m < 4; ++m){
      int ra = wr + m * 16 + lr;
      aoff[kk][m] = ra * 128 + ((((kk * 4 + g) ^ ((ra >> 1) & 7))) << 4);
      int rb = wc + m * 16 + lr;
      boff[kk][m] = 16384 + rb * 128 + ((((kk * 4 + g) ^ ((rb >> 1) & 7))) << 4);
    }
  }

  const bf16* pA[4]; const bf16* pB[4]; int loff[4];
#pragma unroll
  for (int is = 0; is < 4; ++is){
    int f = is * 4096 + wid * 1024 + lane * 16;
    int r = f >> 7, c = (f >> 4) & 7;
    int cg = c ^ ((r >> 1) & 7);
    pA[is] = A  + (size_t)(row0 + r) * K + cg * 8;
    pB[is] = Bt + (size_t)(col0 + r) * K + cg * 8;
    loff[is] = is * 4096 + wid * 1024;
  }

  f32x4 acc[4][4] = {};
  for (int kt = 0; kt < K; kt += 64){
    __syncthreads();
#pragma unroll
    for (int is = 0; is < 4; ++is){
      GLDS16(pA[is] + kt, lds + loff[is]);
      GLDS16(pB[is] + kt, lds + 16384 + loff[is]);
    }
    __syncthreads();
#pragma unroll
    for (int kk = 0; kk < 2; ++kk){
      bf16x8 af[4], bfb[4];
#pragma unroll
      for (int m = 0; m < 4; ++m) af[m] = lds_frag(lds + aoff[kk][m]);
#pragma unroll
      for (int n = 0; n < 4; ++n) bfb[n] = lds_frag(lds + boff[kk][n]);
#pragma unroll
      for (int m = 0; m < 4; ++m)
#pragma unroll
        for (int n = 0; n < 4; ++n)
          acc[m][n] = MFMA16(af[m], bfb[n], acc[m][n]);
    }
  }

  // ---- fused epilogue ----
  int head = (col0 + wc) >> 6;         // 0..47
  int sect = head >> 4;                // 0=q, 1=k, 2=v
  int h = head & 15;
  const float QS = 0.18033688011f;     // 0.125 * log2(e)

  if (sect == 2){
#pragma unroll
    for (int m = 0; m < 4; ++m){
#pragma unroll
      for (int r = 0; r < 4; ++r){
        int s = row0 + wr + m * 16 + g * 4 + r;
        int b = s >> 11, s2 = s & 2047;
        bf16* vp = Vraw + (((size_t)(b * 16 + h)) * 2048 + s2) * 64;
#pragma unroll
        for (int n = 0; n < 4; ++n)
          vp[n * 16 + lr] = (bf16)acc[m][n][r];
      }
    }
  } else {
    bf16* dst = sect ? Kr : Qr;
    float scl = sect ? 1.0f : QS;
#pragma unroll
    for (int m = 0; m < 4; ++m){
#pragma unroll
      for (int r = 0; r < 4; ++r){
        int s = row0 + wr + m * 16 + g * 4 + r;
        int b = s >> 11, s2 = s & 2047;
        bf16* qp = dst + (((size_t)(b * 16 + h)) * 2048 + s2) * 64;
#pragma unroll
        for (int n = 0; n < 2; ++n){
          float x1 = acc[m][n][r], x2 = acc[m][n + 2][r];
          float2 cs = sctab[s2 * 32 + n * 16 + lr];
          qp[n * 16 + lr]      = (bf16)((x1 * cs.x - x2 * cs.y) * scl);
          qp[n * 16 + lr + 32] = (bf16)((x1 * cs.y + x2 * cs.x) * scl);
        }
      }
    }
  }
}

// ---------------- flash attention v7: LDS-staged + KV-split x2 -------------
// grid: 1024 blocks (32 bh x 32 q-blocks of 64); block = 4 waves =
// 2 q-tiles(32q) x 2 kv-halves(1024 keys). 32KB staged K/V (16KB per half,
// shared by the 2 waves of that half). 4 blocks/CU -> 16 waves/CU (50% occ).
// End: 2-way (m,l,O) merge; Olds overlays the K/V staging buffers.
__global__ __launch_bounds__(256, 4) void attn_k(
    const bf16* __restrict__ Q, const bf16* __restrict__ K,
    const bf16* __restrict__ Vt, bf16* __restrict__ AO)
{
  __shared__ __align__(16) char SB[32768];   // [h*8K)=K half h; 16K+[h*8K)=V half h
  __shared__ float mlds[4][2][32];           // [wave][m|l][q]
  __shared__ float invL[2][32];              // [qtile][q]

  int bid = blockIdx.x;
  bid = (bid & 7) * 128 + (bid >> 3);        // XCD chunking (1024 = 8*128)
  int bh = bid >> 5, qb = bid & 31;          // 32 blocks per head, 64 q each
  int b = bh >> 4, h = bh & 15;
  int tid = threadIdx.x, lane = tid & 63, wid = tid >> 6;
  int l31 = lane & 31, hi = lane >> 5, hi8 = hi * 8;
  int qt = wid >> 1, half = wid & 1;
  int q0 = qb * 64 + qt * 32;

  const bf16* Qb = Q  + ((size_t)bh * 2048 + q0) * 64;
  const bf16* Kb = K  + (size_t)bh * 2048 * 64;
  const bf16* Vb = Vt + (size_t)bh * 64 * 2048;
  const bf16* Kh = Kb + (size_t)half * 1024 * 64;
  int vcol0 = half * 1024;

  // Q B-frags: col = q (lane&31), d = t*16 + hi*8 + j (pre-scaled, log2 dom.)
  bf16x8 qf[4];
#pragma unroll
  for (int t = 0; t < 4; ++t)
    qf[t] = g_frag(Qb + (size_t)l31 * 64 + t * 16 + hi8);

  // staging: each wave fills its qt-quarter (4KB) of K and V for its half
  const bf16* pKs[4]; const bf16* pVs[4]; int ldo[4];
#pragma unroll
  for (int is = 0; is < 4; ++is){
    int f = qt * 4096 + is * 1024 + lane * 16;   // byte index in 8KB buffer
    int r = f >> 7;                               // row (key for K, d for V)
    int cg = ((f >> 4) & 7) ^ (r & 7);            // swizzled 16B chunk
    pKs[is] = Kh + (size_t)r * 64 + cg * 8;       // + kv0*64 per chunk
    pVs[is] = Vb + (size_t)r * 2048 + vcol0 + cg * 8;  // + kv0 per chunk
    ldo[is] = qt * 4096 + is * 1024;              // wave-uniform LDS base
  }
  char* klh = SB + half * 8192;
  char* vlh = SB + 16384 + half * 8192;

  f32x16 o0 = {}, o1 = {};     // O[d 0..31][q], O[d 32..63][q]
  float mrun = -1e30f, lrun = 0.0f;

  for (int c = 0; c < 16; ++c){
    int kv0 = c * 64;
    __syncthreads();           // prior chunk's reads complete before overwrite
#pragma unroll
    for (int is = 0; is < 4; ++is){
      GLDS16(pKs[is] + (size_t)kv0 * 64, klh + ldo[is]);
      GLDS16(pVs[is] + kv0,              vlh + ldo[is]);
    }
    __syncthreads();

#pragma unroll
    for (int kk = 0; kk < 2; ++kk){
      int krow = kk * 32 + l31;
      bf16x8 kf[4], vfr[4];
#pragma unroll
      for (int t = 0; t < 4; ++t)
        kf[t] = lds_frag(klh + krow * 128 + ((((2 * t + hi) ^ (krow & 7))) << 4));
#pragma unroll
      for (int u = 0; u < 4; ++u){
        int d = (u & 1) * 32 + l31;
        vfr[u] = lds_frag(vlh + d * 128 +
                          ((((kk * 4) + ((u >> 1) * 2) + hi) ^ (d & 7)) << 4));
      }
      f32x16 sc = {};
#pragma unroll
      for (int t = 0; t < 4; ++t) sc = MFMA32(kf[t], qf[t], sc);

      float a0 = fmaxf(sc[0], sc[1]),   a1 = fmaxf(sc[2], sc[3]);
      float a2 = fmaxf(sc[4], sc[5]),   a3 = fmaxf(sc[6], sc[7]);
      float a4 = fmaxf(sc[8], sc[9]),   a5 = fmaxf(sc[10], sc[11]);
      float a6 = fmaxf(sc[12], sc[13]), a7 = fmaxf(sc[14], sc[15]);
      a0 = fmaxf(a0, a1); a2 = fmaxf(a2, a3);
      a4 = fmaxf(a4, a5); a6 = fmaxf(a6, a7);
      float mt = fmaxf(fmaxf(a0, a2), fmaxf(a4, a6));
      if (!__all(mt - mrun <= 8.0f)){
        mt = fmaxf(mt, __shfl_xor(mt, 32));
        float mn = fmaxf(mrun, mt);
        float cr = __builtin_amdgcn_exp2f(mrun - mn);
#pragma unroll
        for (int r = 0; r < 16; ++r){ o0[r] *= cr; o1[r] *= cr; }
        lrun *= cr; mrun = mn;
      }
#pragma unroll
      for (int r = 0; r < 16; ++r) sc[r] = __builtin_amdgcn_exp2f(sc[r] - mrun);
      float s0 = (sc[0] + sc[1]) + (sc[2] + sc[3]);
      float s1 = (sc[4] + sc[5]) + (sc[6] + sc[7]);
      float s2 = (sc[8] + sc[9]) + (sc[10] + sc[11]);
      float s3 = (sc[12] + sc[13]) + (sc[14] + sc[15]);
      lrun += (s0 + s1) + (s2 + s3);

#pragma unroll
      for (int kh = 0; kh < 2; ++kh){
        unsigned pa0 = pk_bf16(sc[kh * 8 + 0], sc[kh * 8 + 1]);
        unsigned pa1 = pk_bf16(sc[kh * 8 + 2], sc[kh * 8 + 3]);
        unsigned pb0 = pk_bf16(sc[kh * 8 + 4], sc[kh * 8 + 5]);
        unsigned pb1 = pk_bf16(sc[kh * 8 + 6], sc[kh * 8 + 7]);
        p32swap(pa0, pb0); p32swap(pa1, pb1);
        i32x4 wv = { (int)pa0, (int)pa1, (int)pb0, (int)pb1 };
        bf16x8 pf = __builtin_bit_cast(bf16x8, wv);
        o0 = MFMA32(vfr[kh * 2 + 0], pf, o0);
        o1 = MFMA32(vfr[kh * 2 + 1], pf, o1);
      }
    }
  }

  // combine the two half-lane lrun partials (keys split across hi within MFMA)
  lrun += __shfl_xor(lrun, 32);

  // ---- 2-way cross-half merge through LDS ----
  __syncthreads();                             // all K/V reads done
  if (lane < 32){ mlds[wid][0][l31] = mrun; mlds[wid][1][l31] = lrun; }
  __syncthreads();
  float mp = mlds[wid ^ 1][0][l31];
  float M = fmaxf(mrun, mp);
  float ew = __builtin_amdgcn_exp2f(mrun - M);
  if (half == 0 && lane < 32){
    float lp = mlds[wid ^ 1][1][l31];
    invL[qt][l31] = 1.0f / (lrun * ew + lp * __builtin_amdgcn_exp2f(mp - M));
  }
  float* Ow = (float*)SB + wid * 2048;         // [64 d][32 q] per wave
#pragma unroll
  for (int r = 0; r < 16; ++r){
    int d = 8 * (r >> 2) + 4 * hi + (r & 3);
    Ow[d * 32 + l31]        = o0[r] * ew;
    Ow[(d + 32) * 32 + l31] = o1[r] * ew;
  }
  __syncthreads();
  // final: thread -> qt2 = tid>>7, q = tid&31, d-segment = (tid>>5)&3
  int qt2 = tid >> 7, qf31 = tid & 31, dseg = (tid >> 5) & 3;
  const float* Oa = (float*)SB + (2 * qt2) * 2048;
  const float* Ob = (float*)SB + (2 * qt2 + 1) * 2048;
  float iL = invL[qt2][qf31];
  bf16* outp = AO + ((size_t)(b * 2048 + qb * 64 + qt2 * 32 + qf31)) * 1024
                  + h * 64 + dseg * 16;
  bf16x8 w0, w1;
#pragma unroll
  for (int j = 0; j < 8; ++j){
    int d = dseg * 16 + j;
    w0[j] = (bf16)((Oa[d * 32 + qf31] + Ob[d * 32 + qf31]) * iL);
  }
#pragma unroll
  for (int j = 0; j < 8; ++j){
    int d = dseg * 16 + 8 + j;
    w1[j] = (bf16)((Oa[d * 32 + qf31] + Ob[d * 32 + qf31]) * iL);
  }
  *(bf16x8*)outp = w0;
  *(bf16x8*)(outp + 8) = w1;
}

// ---------------------------------------------------------------------------
extern "C" void kernel_launch(void* const* d_in, const int* in_sizes, int n_in,
                              void* d_out, int out_size, void* d_ws, size_t ws_size,
                              hipStream_t stream) {
  const float* x     = (const float*)d_in[0];   // (2,2048,1024)
  const float* w_qkv = (const float*)d_in[1];   // (1024,3072)
  const float* w_out = (const float*)d_in[2];   // (1024,1024)
  float* out = (float*)d_out;                   // (2,2048,1024) f32

  char* ws = (char*)d_ws;
  const size_t MB = 1u << 20;
  unsigned* mm   = (unsigned*)(ws);              // 4 u32
  float2* sctab  = (float2*)(ws + 256);          // 512 KiB (cos,sin)
  bf16* xb       = (bf16*)(ws + 1 * MB);         // 8 MiB
  bf16* wqkvT    = (bf16*)(ws + 9 * MB);         // 6 MiB  (3072 x 1024)
  bf16* woutT    = (bf16*)(ws + 15 * MB);        // 2 MiB  (1024 x 1024)
  bf16* Vraw     = (bf16*)(ws + 17 * MB);        // 8 MiB  (32,2048,64)
  bf16* Qr       = (bf16*)(ws + 65 * MB);        // 8 MiB  (32,2048,64)
  bf16* Kr       = (bf16*)(ws + 73 * MB);        // 8 MiB
  bf16* Vt       = (bf16*)(ws + 81 * MB);        // 8 MiB  (32,64,2048)
  bf16* AO       = (bf16*)(ws + 1 * MB);         // overlay on xb (dead after gemm1)

  init_mm<<<1, 64, 0, stream>>>(mm);
  minmax_k<<<512, 256, 0, stream>>>(w_qkv, 1024 * 3072, mm);
  minmax_k<<<512, 256, 0, stream>>>(w_out, 1024 * 1024, mm + 2);
  sincos_k<<<256, 256, 0, stream>>>(sctab);
  cast_x<<<4096, 256, 0, stream>>>(x, xb, 4194304 / 4);
  dq_t<<<dim3(96, 32), dim3(32, 8), 0, stream>>>(w_qkv, wqkvT, 1024, 3072, mm);
  dq_t<<<dim3(32, 32), dim3(32, 8), 0, stream>>>(w_out, woutT, 1024, 1024, mm + 2);
  gemm_qkv<<<768, 256, 0, stream>>>(xb, wqkvT, sctab, Qr, Kr, Vraw, 4096, 3072, 1024);
  vtrans_b<<<1024, 256, 0, stream>>>(Vraw, Vt);
  attn_k<<<1024, 256, 0, stream>>>(Qr, Kr, Vt, AO);
  gemm_bt<<<256, 256, 0, stream>>>(AO, woutT, out, 4096, 1024, 1024);

  (void)in_sizes; (void)n_in; (void)out_size; (void)ws_size;
}

// Round 8
// 157.414 us; speedup vs baseline: 1.6447x; 1.0354x over previous
//
#include <hip/hip_runtime.h>
#include <hip/hip_bf16.h>

typedef __bf16 bf16;
typedef bf16  bf16x8 __attribute__((ext_vector_type(8)));
typedef bf16  bf16x4 __attribute__((ext_vector_type(4)));
typedef bf16  bf16x2 __attribute__((ext_vector_type(2)));
typedef float f32x4  __attribute__((ext_vector_type(4)));
typedef float f32x16 __attribute__((ext_vector_type(16)));
typedef int   i32x4  __attribute__((ext_vector_type(4)));

#define MFMA16(a,b,c) __builtin_amdgcn_mfma_f32_16x16x32_bf16((a),(b),(c),0,0,0)
#define MFMA32(a,b,c) __builtin_amdgcn_mfma_f32_32x32x16_bf16((a),(b),(c),0,0,0)

#define GLDS16(gp, lp) __builtin_amdgcn_global_load_lds( \
    (const __attribute__((address_space(1))) void*)(void*)(gp), \
    (__attribute__((address_space(3))) void*)(lp), 16, 0, 0)

static __device__ __forceinline__ bf16x8 lds_frag(const char* p){
  i32x4 v = *(const i32x4*)p;
  return __builtin_bit_cast(bf16x8, v);
}
static __device__ __forceinline__ bf16x8 g_frag(const bf16* p){
  i32x4 v = *(const i32x4*)p;
  return __builtin_bit_cast(bf16x8, v);
}
static __device__ __forceinline__ unsigned pk_bf16(float a, float b){
  bf16x2 v = { (bf16)a, (bf16)b };
  return __builtin_bit_cast(unsigned, v);
}
// swap upper 32 lanes of a with lower 32 lanes of b (gfx950)
static __device__ __forceinline__ void p32swap(unsigned &a, unsigned &b){
  asm("v_permlane32_swap_b32 %0, %1" : "+v"(a), "+v"(b));
}
static __device__ __forceinline__ float max3(float a, float b, float c){
  return fmaxf(fmaxf(a, b), c);      // clang fuses to v_max3_f32
}

// ---------------- min/max reduction (order-independent -> deterministic) ---
__device__ __forceinline__ unsigned fmap(float f){
  unsigned u = __float_as_uint(f);
  return (u & 0x80000000u) ? ~u : (u | 0x80000000u);
}
__device__ __forceinline__ float funmap(unsigned m){
  unsigned u = (m & 0x80000000u) ? (m & 0x7FFFFFFFu) : ~m;
  return __uint_as_float(u);
}

__global__ void init_mm(unsigned* mm){
  if (threadIdx.x == 0){
    mm[0] = 0xFFFFFFFFu; mm[1] = 0u;   // w_qkv min,max (mapped)
    mm[2] = 0xFFFFFFFFu; mm[3] = 0u;   // w_out min,max
  }
}

__global__ void minmax_k(const float* __restrict__ w, int n, unsigned* __restrict__ mm){
  __shared__ unsigned smn[256], smx[256];
  int tid = threadIdx.x;
  unsigned lmn = 0xFFFFFFFFu, lmx = 0u;
  for (int i = blockIdx.x * blockDim.x + tid; i < n; i += gridDim.x * blockDim.x){
    unsigned u = fmap(w[i]);
    lmn = min(lmn, u); lmx = max(lmx, u);
  }
  smn[tid] = lmn; smx[tid] = lmx;
  __syncthreads();
  for (int s = 128; s > 0; s >>= 1){
    if (tid < s){
      smn[tid] = min(smn[tid], smn[tid + s]);
      smx[tid] = max(smx[tid], smx[tid + s]);
    }
    __syncthreads();
  }
  if (tid == 0){ atomicMin(&mm[0], smn[0]); atomicMax(&mm[1], smx[0]); }
}

// ------------- fake-quant dequant + transpose + cast to bf16 ---------------
__global__ void dq_t(const float* __restrict__ w, bf16* __restrict__ wt,
                     int R, int C, const unsigned* __restrict__ mm){
  __shared__ float t[32][33];
  float xmin = funmap(mm[0]);
  float xmax = funmap(mm[1]);
  float scale = (xmax - xmin) / 255.0f;
  float denom = scale + 1e-8f;
  int ct = blockIdx.x * 32, rt = blockIdx.y * 32;
  int tx = threadIdx.x, ty = threadIdx.y;   // 32 x 8
#pragma unroll
  for (int p = 0; p < 4; ++p){
    int r = rt + p * 8 + ty;
    float x = w[(size_t)r * C + ct + tx];
    float q = rintf(fminf(fmaxf((x - xmin) / denom, 0.0f), 255.0f));
    t[p * 8 + ty][tx] = q * scale + xmin;
  }
  __syncthreads();
#pragma unroll
  for (int p = 0; p < 4; ++p){
    int c = p * 8 + ty;
    wt[(size_t)(ct + c) * R + rt + tx] = (bf16)t[tx][c];
  }
}

// ---------------- cast x (f32) -> bf16, vectorized x4 ----------------------
__global__ void cast_x(const float* __restrict__ x, bf16* __restrict__ xb, int n4){
  int i = blockIdx.x * 256 + threadIdx.x;
  if (i < n4){
    f32x4 v = *(const f32x4*)(x + (size_t)i * 4);
    bf16x4 o = { (bf16)v.x, (bf16)v.y, (bf16)v.z, (bf16)v.w };
    *(bf16x4*)(xb + (size_t)i * 4) = o;
  }
}

// ---------------- rope table: packed (cos, sin) ----------------------------
__global__ void sincos_k(float2* __restrict__ sctab){
  int idx = blockIdx.x * 256 + threadIdx.x;   // s*32 + i, 65536 total
  int i = idx & 31, s = idx >> 5;
  float invf = powf(10000.0f, -(float)i / 32.0f);
  float fr = (float)s * invf;
  float2 cs; cs.x = cosf(fr); cs.y = sinf(fr);
  sctab[idx] = cs;
}

// ---------------- bf16 MFMA GEMM, C = A * Bt^T (for out-proj) --------------
__global__ __launch_bounds__(256, 2) void gemm_bt(
    const bf16* __restrict__ A, const bf16* __restrict__ Bt,
    float* __restrict__ C, int M, int N, int K)
{
  __shared__ __align__(16) char lds[32768];
  int nbx = N >> 7;
  int bid = blockIdx.x;
  int nwg = gridDim.x;
  if ((nwg & 7) == 0){ int q = nwg >> 3; bid = (bid & 7) * q + (bid >> 3); }
  int row0 = (bid / nbx) << 7;
  int col0 = (bid % nbx) << 7;
  int tid = threadIdx.x, lane = tid & 63, wid = tid >> 6;
  int wr = (wid >> 1) * 64, wc = (wid & 1) * 64;
  int lr = lane & 15, g = lane >> 4;

  int aoff[2][4], boff[2][4];
#pragma unroll
  for (int kk = 0; kk < 2; ++kk){
#pragma unroll
    for (int m = 0; m < 4; ++m){
      int ra = wr + m * 16 + lr;
      aoff[kk][m] = ra * 128 + ((((kk * 4 + g) ^ ((ra >> 1) & 7))) << 4);
      int rb = wc + m * 16 + lr;
      boff[kk][m] = 16384 + rb * 128 + ((((kk * 4 + g) ^ ((rb >> 1) & 7))) << 4);
    }
  }

  const bf16* pA[4]; const bf16* pB[4]; int loff[4];
#pragma unroll
  for (int is = 0; is < 4; ++is){
    int f = is * 4096 + wid * 1024 + lane * 16;
    int r = f >> 7, c = (f >> 4) & 7;
    int cg = c ^ ((r >> 1) & 7);
    pA[is] = A  + (size_t)(row0 + r) * K + cg * 8;
    pB[is] = Bt + (size_t)(col0 + r) * K + cg * 8;
    loff[is] = is * 4096 + wid * 1024;
  }

  f32x4 acc[4][4] = {};
  for (int kt = 0; kt < K; kt += 64){
    __syncthreads();
#pragma unroll
    for (int is = 0; is < 4; ++is){
      GLDS16(pA[is] + kt, lds + loff[is]);
      GLDS16(pB[is] + kt, lds + 16384 + loff[is]);
    }
    __syncthreads();
#pragma unroll
    for (int kk = 0; kk < 2; ++kk){
      bf16x8 af[4], bfb[4];
#pragma unroll
      for (int m = 0; m < 4; ++m) af[m] = lds_frag(lds + aoff[kk][m]);
#pragma unroll
      for (int n = 0; n < 4; ++n) bfb[n] = lds_frag(lds + boff[kk][n]);
#pragma unroll
      for (int m = 0; m < 4; ++m)
#pragma unroll
        for (int n = 0; n < 4; ++n)
          acc[m][n] = MFMA16(af[m], bfb[n], acc[m][n]);
    }
  }

#pragma unroll
  for (int m = 0; m < 4; ++m){
    int row = row0 + wr + m * 16 + g * 4;
#pragma unroll
    for (int n = 0; n < 4; ++n){
      int col = col0 + wc + n * 16 + lr;
      float* cp = C + (size_t)row * N + col;
#pragma unroll
      for (int r = 0; r < 4; ++r)
        cp[(size_t)r * N] = acc[m][n][r];
    }
  }
}

// ------- QKV GEMM with fused RoPE/split epilogue + direct-Vt write ---------
// C-tile cols map to (sect,h,d): head = col/64, sect = head>>4 (q/k/v).
// RoPE pair (d, d+32) lives in (acc[m][n], acc[m][n+2]) of the SAME thread.
// Writes Qr (RoPE, pre-scaled by 0.125*log2e), Kr (RoPE), and Vt TRANSPOSED
// (B,H,D,S): r=0..3 of acc[m][n] are 4 consecutive s at fixed d -> bf16x4.
__global__ __launch_bounds__(256, 2) void gemm_qkv(
    const bf16* __restrict__ A, const bf16* __restrict__ Bt,
    const float2* __restrict__ sctab,
    bf16* __restrict__ Qr, bf16* __restrict__ Kr, bf16* __restrict__ Vt,
    int M, int N, int K)
{
  __shared__ __align__(16) char lds[32768];
  int nbx = N >> 7;
  int bid = blockIdx.x;
  int nwg = gridDim.x;
  if ((nwg & 7) == 0){ int q = nwg >> 3; bid = (bid & 7) * q + (bid >> 3); }
  int row0 = (bid / nbx) << 7;
  int col0 = (bid % nbx) << 7;
  int tid = threadIdx.x, lane = tid & 63, wid = tid >> 6;
  int wr = (wid >> 1) * 64, wc = (wid & 1) * 64;
  int lr = lane & 15, g = lane >> 4;

  int aoff[2][4], boff[2][4];
#pragma unroll
  for (int kk = 0; kk < 2; ++kk){
#pragma unroll
    for (int m = 0; m < 4; ++m){
      int ra = wr + m * 16 + lr;
      aoff[kk][m] = ra * 128 + ((((kk * 4 + g) ^ ((ra >> 1) & 7))) << 4);
      int rb = wc + m * 16 + lr;
      boff[kk][m] = 16384 + rb * 128 + ((((kk * 4 + g) ^ ((rb >> 1) & 7))) << 4);
    }
  }

  const bf16* pA[4]; const bf16* pB[4]; int loff[4];
#pragma unroll
  for (int is = 0; is < 4; ++is){
    int f = is * 4096 + wid * 1024 + lane * 16;
    int r = f >> 7, c = (f >> 4) & 7;
    int cg = c ^ ((r >> 1) & 7);
    pA[is] = A  + (size_t)(row0 + r) * K + cg * 8;
    pB[is] = Bt + (size_t)(col0 + r) * K + cg * 8;
    loff[is] = is * 4096 + wid * 1024;
  }

  f32x4 acc[4][4] = {};
  for (int kt = 0; kt < K; kt += 64){
    __syncthreads();
#pragma unroll
    for (int is = 0; is < 4; ++is){
      GLDS16(pA[is] + kt, lds + loff[is]);
      GLDS16(pB[is] + kt, lds + 16384 + loff[is]);
    }
    __syncthreads();
#pragma unroll
    for (int kk = 0; kk < 2; ++kk){
      bf16x8 af[4], bfb[4];
#pragma unroll
      for (int m = 0; m < 4; ++m) af[m] = lds_frag(lds + aoff[kk][m]);
#pragma unroll
      for (int n = 0; n < 4; ++n) bfb[n] = lds_frag(lds + boff[kk][n]);
#pragma unroll
      for (int m = 0; m < 4; ++m)
#pragma unroll
        for (int n = 0; n < 4; ++n)
          acc[m][n] = MFMA16(af[m], bfb[n], acc[m][n]);
    }
  }

  // ---- fused epilogue ----
  int head = (col0 + wc) >> 6;         // 0..47
  int sect = head >> 4;                // 0=q, 1=k, 2=v
  int h = head & 15;
  const float QS = 0.18033688011f;     // 0.125 * log2(e)

  if (sect == 2){
    // V: write transposed (B,H,D,S). d = n*16+lr; s base = row (4-aligned).
#pragma unroll
    for (int m = 0; m < 4; ++m){
      int s = row0 + wr + m * 16 + g * 4;
      int b = s >> 11, s2 = s & 2047;
#pragma unroll
      for (int n = 0; n < 4; ++n){
        int d = n * 16 + lr;
        bf16x4 v4 = { (bf16)acc[m][n][0], (bf16)acc[m][n][1],
                      (bf16)acc[m][n][2], (bf16)acc[m][n][3] };
        *(bf16x4*)(Vt + (((size_t)(b * 16 + h)) * 64 + d) * 2048 + s2) = v4;
      }
    }
  } else {
    bf16* dst = sect ? Kr : Qr;
    float scl = sect ? 1.0f : QS;
#pragma unroll
    for (int m = 0; m < 4; ++m){
#pragma unroll
      for (int r = 0; r < 4; ++r){
        int s = row0 + wr + m * 16 + g * 4 + r;
        int b = s >> 11, s2 = s & 2047;
        bf16* qp = dst + (((size_t)(b * 16 + h)) * 2048 + s2) * 64;
#pragma unroll
        for (int n = 0; n < 2; ++n){
          float x1 = acc[m][n][r], x2 = acc[m][n + 2][r];
          float2 cs = sctab[s2 * 32 + n * 16 + lr];
          qp[n * 16 + lr]      = (bf16)((x1 * cs.x - x2 * cs.y) * scl);
          qp[n * 16 + lr + 32] = (bf16)((x1 * cs.y + x2 * cs.x) * scl);
        }
      }
    }
  }
}

// ---------------- flash attention v8: 32KB LDS, 4 blocks/CU ----------------
// grid: 1024 blocks (32 bh x 32 q-blocks of 64); block = 4 waves =
// 2 q-tiles(32q) x 2 kv-halves(1024 keys). 32KB staged K/V. LDS EXACTLY
// 32768 B -> 4 blocks/CU -> 16 waves/CU. End-phase 2-way merge reuses SB
// (m/l exchange then O-merge), each wave computes merged inv redundantly.
__global__ __launch_bounds__(256, 4) void attn_k(
    const bf16* __restrict__ Q, const bf16* __restrict__ K,
    const bf16* __restrict__ Vt, bf16* __restrict__ AO)
{
  __shared__ __align__(16) char SB[32768];   // staging, then merge buffer

  int bid = blockIdx.x;
  bid = (bid & 7) * 128 + (bid >> 3);        // XCD chunking (1024 = 8*128)
  int bh = bid >> 5, qb = bid & 31;          // 32 blocks per head, 64 q each
  int b = bh >> 4, h = bh & 15;
  int tid = threadIdx.x, lane = tid & 63, wid = tid >> 6;
  int l31 = lane & 31, hi = lane >> 5, hi8 = hi * 8;
  int qt = wid >> 1, half = wid & 1;
  int q0 = qb * 64 + qt * 32;

  const bf16* Qb = Q  + ((size_t)bh * 2048 + q0) * 64;
  const bf16* Kb = K  + (size_t)bh * 2048 * 64;
  const bf16* Vb = Vt + (size_t)bh * 64 * 2048;
  const bf16* Kh = Kb + (size_t)half * 1024 * 64;
  int vcol0 = half * 1024;

  // Q B-frags: col = q (lane&31), d = t*16 + hi*8 + j (pre-scaled, log2 dom.)
  bf16x8 qf[4];
#pragma unroll
  for (int t = 0; t < 4; ++t)
    qf[t] = g_frag(Qb + (size_t)l31 * 64 + t * 16 + hi8);

  // staging: each wave fills its qt-quarter (4KB) of K and V for its half
  const bf16* pKs[4]; const bf16* pVs[4]; int ldo[4];
#pragma unroll
  for (int is = 0; is < 4; ++is){
    int f = qt * 4096 + is * 1024 + lane * 16;   // byte index in 8KB buffer
    int r = f >> 7;                               // row (key for K, d for V)
    int cg = ((f >> 4) & 7) ^ (r & 7);            // swizzled 16B chunk
    pKs[is] = Kh + (size_t)r * 64 + cg * 8;       // + kv0*64 per chunk
    pVs[is] = Vb + (size_t)r * 2048 + vcol0 + cg * 8;  // + kv0 per chunk
    ldo[is] = qt * 4096 + is * 1024;              // wave-uniform LDS base
  }
  char* klh = SB + half * 8192;
  char* vlh = SB + 16384 + half * 8192;

  f32x16 o0 = {}, o1 = {};     // O[d 0..31][q], O[d 32..63][q]
  float mrun = -1e30f, lrun = 0.0f;

  for (int c = 0; c < 16; ++c){
    int kv0 = c * 64;
    __syncthreads();           // prior chunk's reads complete before overwrite
#pragma unroll
    for (int is = 0; is < 4; ++is){
      GLDS16(pKs[is] + (size_t)kv0 * 64, klh + ldo[is]);
      GLDS16(pVs[is] + kv0,              vlh + ldo[is]);
    }
    __syncthreads();

#pragma unroll
    for (int kk = 0; kk < 2; ++kk){
      int krow = kk * 32 + l31;
      bf16x8 kf[4], vfr[4];
#pragma unroll
      for (int t = 0; t < 4; ++t)
        kf[t] = lds_frag(klh + krow * 128 + ((((2 * t + hi) ^ (krow & 7))) << 4));
#pragma unroll
      for (int u = 0; u < 4; ++u){
        int d = (u & 1) * 32 + l31;
        vfr[u] = lds_frag(vlh + d * 128 +
                          ((((kk * 4) + ((u >> 1) * 2) + hi) ^ (d & 7)) << 4));
      }
      f32x16 sc = {};
#pragma unroll
      for (int t = 0; t < 4; ++t) sc = MFMA32(kf[t], qf[t], sc);

      // max via v_max3 nests: 16 -> 7 ops
      float t0 = max3(sc[0], sc[1], sc[2]);
      float t1 = max3(sc[3], sc[4], sc[5]);
      float t2 = max3(sc[6], sc[7], sc[8]);
      float t3 = max3(sc[9], sc[10], sc[11]);
      float t4 = max3(sc[12], sc[13], sc[14]);
      float mt = fmaxf(max3(t0, t1, t2), max3(t3, t4, sc[15]));
      if (!__all(mt - mrun <= 8.0f)){
        mt = fmaxf(mt, __shfl_xor(mt, 32));
        float mn = fmaxf(mrun, mt);
        float cr = __builtin_amdgcn_exp2f(mrun - mn);
#pragma unroll
        for (int r = 0; r < 16; ++r){ o0[r] *= cr; o1[r] *= cr; }
        lrun *= cr; mrun = mn;
      }
#pragma unroll
      for (int r = 0; r < 16; ++r) sc[r] = __builtin_amdgcn_exp2f(sc[r] - mrun);
      float s0 = (sc[0] + sc[1]) + (sc[2] + sc[3]);
      float s1 = (sc[4] + sc[5]) + (sc[6] + sc[7]);
      float s2 = (sc[8] + sc[9]) + (sc[10] + sc[11]);
      float s3 = (sc[12] + sc[13]) + (sc[14] + sc[15]);
      lrun += (s0 + s1) + (s2 + s3);

#pragma unroll
      for (int kh = 0; kh < 2; ++kh){
        unsigned pa0 = pk_bf16(sc[kh * 8 + 0], sc[kh * 8 + 1]);
        unsigned pa1 = pk_bf16(sc[kh * 8 + 2], sc[kh * 8 + 3]);
        unsigned pb0 = pk_bf16(sc[kh * 8 + 4], sc[kh * 8 + 5]);
        unsigned pb1 = pk_bf16(sc[kh * 8 + 6], sc[kh * 8 + 7]);
        p32swap(pa0, pb0); p32swap(pa1, pb1);
        i32x4 wv = { (int)pa0, (int)pa1, (int)pb0, (int)pb1 };
        bf16x8 pf = __builtin_bit_cast(bf16x8, wv);
        o0 = MFMA32(vfr[kh * 2 + 0], pf, o0);
        o1 = MFMA32(vfr[kh * 2 + 1], pf, o1);
      }
    }
  }

  // combine the two half-lane lrun partials (keys split across hi within MFMA)
  lrun += __shfl_xor(lrun, 32);

  // ---- 2-way cross-half merge, reusing SB (no extra LDS) ----
  __syncthreads();                             // all K/V reads done
  float* ml = (float*)SB;                      // [wave][m(32)|l(32)]
  if (lane < 32){ ml[wid * 64 + l31] = mrun; ml[wid * 64 + 32 + l31] = lrun; }
  __syncthreads();
  float mp = ml[(wid ^ 1) * 64 + l31];
  float lp = ml[(wid ^ 1) * 64 + 32 + l31];
  __syncthreads();                             // m/l reads done before O-write
  float M = fmaxf(mrun, mp);
  float ew = __builtin_amdgcn_exp2f(mrun - M);
  float ep = __builtin_amdgcn_exp2f(mp - M);
  float inv = ew / (lrun * ew + lp * ep);      // merged 1/L * my-half weight
  float* Ow = (float*)SB + wid * 2048;         // [64 d][32 q] per wave
#pragma unroll
  for (int r = 0; r < 16; ++r){
    int d = 8 * (r >> 2) + 4 * hi + (r & 3);
    Ow[d * 32 + l31]        = o0[r] * inv;
    Ow[(d + 32) * 32 + l31] = o1[r] * inv;
  }
  __syncthreads();
  // final: thread -> qt2 = tid>>7, q = tid&31, d-segment = (tid>>5)&3
  int qt2 = tid >> 7, qf31 = tid & 31, dseg = (tid >> 5) & 3;
  const float* Oa = (float*)SB + (2 * qt2) * 2048;
  const float* Ob = (float*)SB + (2 * qt2 + 1) * 2048;
  bf16* outp = AO + ((size_t)(b * 2048 + qb * 64 + qt2 * 32 + qf31)) * 1024
                  + h * 64 + dseg * 16;
  bf16x8 w0, w1;
#pragma unroll
  for (int j = 0; j < 8; ++j){
    int d = dseg * 16 + j;
    w0[j] = (bf16)(Oa[d * 32 + qf31] + Ob[d * 32 + qf31]);
  }
#pragma unroll
  for (int j = 0; j < 8; ++j){
    int d = dseg * 16 + 8 + j;
    w1[j] = (bf16)(Oa[d * 32 + qf31] + Ob[d * 32 + qf31]);
  }
  *(bf16x8*)outp = w0;
  *(bf16x8*)(outp + 8) = w1;
}

// ---------------------------------------------------------------------------
extern "C" void kernel_launch(void* const* d_in, const int* in_sizes, int n_in,
                              void* d_out, int out_size, void* d_ws, size_t ws_size,
                              hipStream_t stream) {
  const float* x     = (const float*)d_in[0];   // (2,2048,1024)
  const float* w_qkv = (const float*)d_in[1];   // (1024,3072)
  const float* w_out = (const float*)d_in[2];   // (1024,1024)
  float* out = (float*)d_out;                   // (2,2048,1024) f32

  char* ws = (char*)d_ws;
  const size_t MB = 1u << 20;
  unsigned* mm   = (unsigned*)(ws);              // 4 u32
  float2* sctab  = (float2*)(ws + 256);          // 512 KiB (cos,sin)
  bf16* xb       = (bf16*)(ws + 1 * MB);         // 8 MiB
  bf16* wqkvT    = (bf16*)(ws + 9 * MB);         // 6 MiB  (3072 x 1024)
  bf16* woutT    = (bf16*)(ws + 15 * MB);        // 2 MiB  (1024 x 1024)
  bf16* Qr       = (bf16*)(ws + 65 * MB);        // 8 MiB  (32,2048,64)
  bf16* Kr       = (bf16*)(ws + 73 * MB);        // 8 MiB
  bf16* Vt       = (bf16*)(ws + 81 * MB);        // 8 MiB  (32,64,2048)
  bf16* AO       = (bf16*)(ws + 1 * MB);         // overlay on xb (dead after gemm_qkv)

  init_mm<<<1, 64, 0, stream>>>(mm);
  minmax_k<<<512, 256, 0, stream>>>(w_qkv, 1024 * 3072, mm);
  minmax_k<<<512, 256, 0, stream>>>(w_out, 1024 * 1024, mm + 2);
  sincos_k<<<256, 256, 0, stream>>>(sctab);
  cast_x<<<4096, 256, 0, stream>>>(x, xb, 4194304 / 4);
  dq_t<<<dim3(96, 32), dim3(32, 8), 0, stream>>>(w_qkv, wqkvT, 1024, 3072, mm);
  dq_t<<<dim3(32, 32), dim3(32, 8), 0, stream>>>(w_out, woutT, 1024, 1024, mm + 2);
  gemm_qkv<<<768, 256, 0, stream>>>(xb, wqkvT, sctab, Qr, Kr, Vt, 4096, 3072, 1024);
  attn_k<<<1024, 256, 0, stream>>>(Qr, Kr, Vt, AO);
  gemm_bt<<<256, 256, 0, stream>>>(AO, woutT, out, 4096, 1024, 1024);

  (void)in_sizes; (void)n_in; (void)out_size; (void)ws_size;
}